// Round 1
// baseline (252.673 us; speedup 1.0000x reference)
//
#include <hip/hip_runtime.h>
#include <math.h>

#define DM 192       // d_model == d_inner
#define RNK 12
#define NS 16
#define PB 4096      // H*W
#define NPOS 8192    // B*H*W
#define NO2 432      // fused phase-2 outputs: 192 dT | 192 dL | 48 bc

// workspace float offsets
#define OFF_WINT   0u
#define OFF_WCOMB  36864u
#define OFF_WOT    119808u
#define OFF_U      156672u
#define OFF_DT     1729536u
#define OFF_DL     3302400u
#define OFF_BC     4875264u
#define OFF_YG     5268480u
// total 6,841,344 floats = 27.4 MB

__device__ __forceinline__ float gelu_f(float x){
    return 0.5f * x * (1.0f + erff(x * 0.70710678118654752f));
}
__device__ __forceinline__ float softplus_f(float x){
    return fmaxf(x, 0.0f) + log1pf(__expf(-fabsf(x)));
}

// ---------------- prep: transposes + combined dt-projection weight ----------------
__global__ __launch_bounds__(256) void prep_k(const float* __restrict__ Win,
                                              const float* __restrict__ xpw,
                                              const float* __restrict__ dtwT,
                                              const float* __restrict__ dtwL,
                                              const float* __restrict__ Wout,
                                              float* __restrict__ ws){
    int idx = blockIdx.x * 256 + threadIdx.x;
    if (idx < 36864){                       // W_inT[c][d] = Win[d][c]
        int c = idx / DM, d = idx % DM;
        ws[OFF_WINT + idx] = Win[d * DM + c];
    } else if (idx < 73728){                // W_oT[d][c] = Wout[c][d]
        int t = idx - 36864;
        int d = t / DM, c = t % DM;
        ws[OFF_WOT + t] = Wout[c * DM + d];
    } else if (idx < 156672){               // WcombT[c][o]
        int t = idx - 73728;
        int c = t / NO2, o = t % NO2;
        float acc = 0.f;
        if (o < 192){
            #pragma unroll
            for (int r = 0; r < RNK; r++) acc += dtwT[o * RNK + r] * xpw[r * DM + c];
        } else if (o < 384){
            int d2 = o - 192;
            #pragma unroll
            for (int r = 0; r < RNK; r++) acc += dtwL[d2 * RNK + r] * xpw[(RNK + r) * DM + c];
        } else {
            acc = xpw[(2 * RNK + (o - 384)) * DM + c];
        }
        ws[OFF_WCOMB + t] = acc;
    }
}

// ---------------- fused projections: x -> u(gelu) -> {deltaT, deltaL, B_T,B_L,C} ----------------
__global__ __launch_bounds__(256) void proj_k(const float* __restrict__ x,
                                              const float* __restrict__ inb,
                                              const float* __restrict__ dtTb,
                                              const float* __restrict__ dtLb,
                                              float* __restrict__ ws){
    __shared__ float x_t[16][196];
    __shared__ float u_t[16][196];
    const float* __restrict__ WinT = ws + OFF_WINT;
    const float* __restrict__ Wc   = ws + OFF_WCOMB;
    float* __restrict__ u_ws  = ws + OFF_U;
    float* __restrict__ dT_ws = ws + OFF_DT;
    float* __restrict__ dL_ws = ws + OFF_DL;
    float* __restrict__ bc_ws = ws + OFF_BC;

    const int p0 = blockIdx.x * 16;
    const int b = p0 >> 12;
    const int prel = p0 & 4095;
    const int tid = threadIdx.x;

    for (int i = tid; i < 16 * 192; i += 256){
        int pp = i / 192, c = i - pp * 192;
        x_t[pp][c] = x[(size_t)(p0 + pp) * 192 + c];
    }
    __syncthreads();

    // phase 1: u = gelu(x @ W_in^T + b); 192 threads: (td 0..47)*4 d x (tp 0..3)*4 pos
    if (tid < 192){
        const int td = tid % 48, tp = tid / 48;
        const int d0 = td * 4, pr = tp * 4;
        float acc[4][4];
        #pragma unroll
        for (int a = 0; a < 4; a++)
            #pragma unroll
            for (int bnk = 0; bnk < 4; bnk++) acc[a][bnk] = 0.f;
        for (int c = 0; c < 192; c += 4){
            float4 w0 = *(const float4*)&WinT[(c + 0) * 192 + d0];
            float4 w1 = *(const float4*)&WinT[(c + 1) * 192 + d0];
            float4 w2 = *(const float4*)&WinT[(c + 2) * 192 + d0];
            float4 w3 = *(const float4*)&WinT[(c + 3) * 192 + d0];
            #pragma unroll
            for (int pi = 0; pi < 4; pi++){
                float4 xv = *(const float4*)&x_t[pr + pi][c];
                acc[pi][0] = fmaf(xv.x, w0.x, fmaf(xv.y, w1.x, fmaf(xv.z, w2.x, fmaf(xv.w, w3.x, acc[pi][0]))));
                acc[pi][1] = fmaf(xv.x, w0.y, fmaf(xv.y, w1.y, fmaf(xv.z, w2.y, fmaf(xv.w, w3.y, acc[pi][1]))));
                acc[pi][2] = fmaf(xv.x, w0.z, fmaf(xv.y, w1.z, fmaf(xv.z, w2.z, fmaf(xv.w, w3.z, acc[pi][2]))));
                acc[pi][3] = fmaf(xv.x, w0.w, fmaf(xv.y, w1.w, fmaf(xv.z, w2.w, fmaf(xv.w, w3.w, acc[pi][3]))));
            }
        }
        float4 bv = *(const float4*)&inb[d0];
        float g[4][4];
        #pragma unroll
        for (int pi = 0; pi < 4; pi++){
            g[pi][0] = gelu_f(acc[pi][0] + bv.x);
            g[pi][1] = gelu_f(acc[pi][1] + bv.y);
            g[pi][2] = gelu_f(acc[pi][2] + bv.z);
            g[pi][3] = gelu_f(acc[pi][3] + bv.w);
        }
        #pragma unroll
        for (int pi = 0; pi < 4; pi++){
            *(float4*)&u_t[pr + pi][d0] = make_float4(g[pi][0], g[pi][1], g[pi][2], g[pi][3]);
        }
        #pragma unroll
        for (int dk = 0; dk < 4; dk++){
            *(float4*)&u_ws[(size_t)(b * 192 + d0 + dk) * 4096 + prel + pr] =
                make_float4(g[0][dk], g[1][dk], g[2][dk], g[3][dk]);
        }
    }
    __syncthreads();

    // phase 2: [dT | dL | bc] = u @ WcombT ; 216 threads: (td 0..107)*4 o x (tp2 0..1)*8 pos
    if (tid < 216){
        const int td = tid % 108, tp2 = tid / 108;
        const int o0 = td * 4, pr = tp2 * 8;
        float acc[8][4];
        #pragma unroll
        for (int a = 0; a < 8; a++)
            #pragma unroll
            for (int bnk = 0; bnk < 4; bnk++) acc[a][bnk] = 0.f;
        for (int c = 0; c < 192; c += 4){
            float4 w0 = *(const float4*)&Wc[(c + 0) * NO2 + o0];
            float4 w1 = *(const float4*)&Wc[(c + 1) * NO2 + o0];
            float4 w2 = *(const float4*)&Wc[(c + 2) * NO2 + o0];
            float4 w3 = *(const float4*)&Wc[(c + 3) * NO2 + o0];
            #pragma unroll
            for (int pi = 0; pi < 8; pi++){
                float4 xv = *(const float4*)&u_t[pr + pi][c];
                acc[pi][0] = fmaf(xv.x, w0.x, fmaf(xv.y, w1.x, fmaf(xv.z, w2.x, fmaf(xv.w, w3.x, acc[pi][0]))));
                acc[pi][1] = fmaf(xv.x, w0.y, fmaf(xv.y, w1.y, fmaf(xv.z, w2.y, fmaf(xv.w, w3.y, acc[pi][1]))));
                acc[pi][2] = fmaf(xv.x, w0.z, fmaf(xv.y, w1.z, fmaf(xv.z, w2.z, fmaf(xv.w, w3.z, acc[pi][2]))));
                acc[pi][3] = fmaf(xv.x, w0.w, fmaf(xv.y, w1.w, fmaf(xv.z, w2.w, fmaf(xv.w, w3.w, acc[pi][3]))));
            }
        }
        if (o0 < 192){
            #pragma unroll
            for (int ok = 0; ok < 4; ok++){
                int d = o0 + ok;
                float bb = dtTb[d];
                float v[8];
                #pragma unroll
                for (int pi = 0; pi < 8; pi++) v[pi] = softplus_f(acc[pi][ok] + bb);
                float* dst = &dT_ws[(size_t)(b * 192 + d) * 4096 + prel + pr];
                *(float4*)&dst[0] = make_float4(v[0], v[1], v[2], v[3]);
                *(float4*)&dst[4] = make_float4(v[4], v[5], v[6], v[7]);
            }
        } else if (o0 < 384){
            #pragma unroll
            for (int ok = 0; ok < 4; ok++){
                int d = o0 - 192 + ok;
                float bb = dtLb[d];
                float v[8];
                #pragma unroll
                for (int pi = 0; pi < 8; pi++) v[pi] = softplus_f(acc[pi][ok] + bb);
                float* dst = &dL_ws[(size_t)(b * 192 + d) * 4096 + prel + pr];
                *(float4*)&dst[0] = make_float4(v[0], v[1], v[2], v[3]);
                *(float4*)&dst[4] = make_float4(v[4], v[5], v[6], v[7]);
            }
        } else {
            int col = o0 - 384;
            #pragma unroll
            for (int pi = 0; pi < 8; pi++){
                *(float4*)&bc_ws[(size_t)(p0 + pr + pi) * 48 + col] =
                    make_float4(acc[pi][0], acc[pi][1], acc[pi][2], acc[pi][3]);
            }
        }
    }
}

// ---------------- diagonal wavefront scan: block per (b,d), 4 waves split 16 states ----------------
__global__ __launch_bounds__(256) void scan_k(const float* __restrict__ ATl,
                                              const float* __restrict__ ALl,
                                              const float* __restrict__ Dskp,
                                              float* __restrict__ ws){
    const int bd = blockIdx.x;
    const int b = bd / 192, d = bd - b * 192;
    const int tid = threadIdx.x;
    const int wv = tid >> 6, j = tid & 63;
    const int n0 = wv << 2;

    const float* __restrict__ dTp = ws + OFF_DT + (size_t)bd * 4096;
    const float* __restrict__ dLp = ws + OFF_DL + (size_t)bd * 4096;
    const float* __restrict__ up  = ws + OFF_U  + (size_t)bd * 4096;
    const float4* __restrict__ bcp = (const float4*)(ws + OFF_BC + (size_t)b * 4096 * 48);
    float* __restrict__ yg = ws + OFF_YG + (size_t)bd * 4096;

    float AT[4], AL[4], h[4];
    #pragma unroll
    for (int k = 0; k < 4; k++){
        AT[k] = -expf(ATl[d * NS + n0 + k]);
        AL[k] = -expf(ALl[d * NS + n0 + k]);
        h[k] = 0.f;
    }
    const float Dsk = Dskp[d];

    __shared__ float ypart[2][4][64];

    // prefetch step 0
    int icl = min(max(0 - j, 0), 63);
    int off = icl * 64 + j;
    float dT_n = dTp[off], dL_n = dLp[off], u_n = up[off];
    float4 BTn = bcp[off * 12 + wv];
    float4 BLn = bcp[off * 12 + 4 + wv];
    float4 Cn  = bcp[off * 12 + 8 + wv];

    for (int s = 0; s < 127; s++){
        const float dT_c = dT_n, dL_c = dL_n, u_c = u_n;
        float bt[4], bl[4], cc[4];
        *(float4*)&bt[0] = BTn;
        *(float4*)&bl[0] = BLn;
        *(float4*)&cc[0] = Cn;
        const int i_c = s - j;
        const bool act = (i_c >= 0) && (i_c < 64);

        // prefetch step s+1
        int i2 = min(max(s + 1 - j, 0), 63);
        int off2 = i2 * 64 + j;
        dT_n = dTp[off2]; dL_n = dLp[off2]; u_n = up[off2];
        BTn = bcp[off2 * 12 + wv];
        BLn = bcp[off2 * 12 + 4 + wv];
        Cn  = bcp[off2 * 12 + 8 + wv];

        const float udT = u_c * dT_c, udL = u_c * dL_c;
        float y = 0.f;
        #pragma unroll
        for (int k = 0; k < 4; k++){
            const float dATk = __expf(dT_c * AT[k]);
            const float dALk = __expf(dL_c * AL[k]);
            float hl = __shfl_up(h[k], 1u, 64);
            hl = (j == 0) ? 0.f : hl;
            const float hn = fmaf(dATk, h[k], fmaf(dALk, hl, fmaf(udT, bt[k], udL * bl[k])));
            h[k] = act ? hn : h[k];
            y = fmaf(hn, cc[k], y);
        }
        ypart[s & 1][wv][j] = y;
        __syncthreads();
        if (wv == 0 && act){
            const float yt = ypart[s & 1][0][j] + ypart[s & 1][1][j] +
                             ypart[s & 1][2][j] + ypart[s & 1][3][j] + u_c * Dsk;
            yg[i_c * 64 + j] = gelu_f(yt);
        }
    }
}

// ---------------- out projection: out = gelu_y @ W_o^T + b ----------------
__global__ __launch_bounds__(256) void out_k(const float* __restrict__ Wob,
                                             float* __restrict__ ws,
                                             float* __restrict__ out){
    __shared__ float yg_t[16][196];
    const float* __restrict__ WoT = ws + OFF_WOT;
    const float* __restrict__ yg  = ws + OFF_YG;
    const int p0 = blockIdx.x * 16;
    const int b = p0 >> 12;
    const int prel = p0 & 4095;
    const int tid = threadIdx.x;

    if (tid < 192){
        const float* src = yg + (size_t)(b * 192 + tid) * 4096 + prel;
        #pragma unroll
        for (int q = 0; q < 4; q++){
            float4 v = *(const float4*)&src[q * 4];
            yg_t[q * 4 + 0][tid] = v.x;
            yg_t[q * 4 + 1][tid] = v.y;
            yg_t[q * 4 + 2][tid] = v.z;
            yg_t[q * 4 + 3][tid] = v.w;
        }
    }
    __syncthreads();

    if (tid < 192){
        const int td = tid % 48, tp = tid / 48;
        const int c0 = td * 4, pr = tp * 4;
        float acc[4][4];
        #pragma unroll
        for (int a = 0; a < 4; a++)
            #pragma unroll
            for (int bnk = 0; bnk < 4; bnk++) acc[a][bnk] = 0.f;
        for (int dd = 0; dd < 192; dd += 4){
            float4 w0 = *(const float4*)&WoT[(dd + 0) * 192 + c0];
            float4 w1 = *(const float4*)&WoT[(dd + 1) * 192 + c0];
            float4 w2 = *(const float4*)&WoT[(dd + 2) * 192 + c0];
            float4 w3 = *(const float4*)&WoT[(dd + 3) * 192 + c0];
            #pragma unroll
            for (int pi = 0; pi < 4; pi++){
                float4 xv = *(const float4*)&yg_t[pr + pi][dd];
                acc[pi][0] = fmaf(xv.x, w0.x, fmaf(xv.y, w1.x, fmaf(xv.z, w2.x, fmaf(xv.w, w3.x, acc[pi][0]))));
                acc[pi][1] = fmaf(xv.x, w0.y, fmaf(xv.y, w1.y, fmaf(xv.z, w2.y, fmaf(xv.w, w3.y, acc[pi][1]))));
                acc[pi][2] = fmaf(xv.x, w0.z, fmaf(xv.y, w1.z, fmaf(xv.z, w2.z, fmaf(xv.w, w3.z, acc[pi][2]))));
                acc[pi][3] = fmaf(xv.x, w0.w, fmaf(xv.y, w1.w, fmaf(xv.z, w2.w, fmaf(xv.w, w3.w, acc[pi][3]))));
            }
        }
        float4 bv = *(const float4*)&Wob[c0];
        #pragma unroll
        for (int pi = 0; pi < 4; pi++){
            float4 ov = make_float4(acc[pi][0] + bv.x, acc[pi][1] + bv.y,
                                    acc[pi][2] + bv.z, acc[pi][3] + bv.w);
            *(float4*)&out[(size_t)(p0 + pr + pi) * 192 + c0] = ov;
        }
    }
}

extern "C" void kernel_launch(void* const* d_in, const int* in_sizes, int n_in,
                              void* d_out, int out_size, void* d_ws, size_t ws_size,
                              hipStream_t stream) {
    const float* x    = (const float*)d_in[0];
    const float* Win  = (const float*)d_in[1];
    const float* Winb = (const float*)d_in[2];
    const float* xpw  = (const float*)d_in[3];
    const float* dtTw = (const float*)d_in[4];
    const float* dtTb = (const float*)d_in[5];
    const float* dtLw = (const float*)d_in[6];
    const float* dtLb = (const float*)d_in[7];
    const float* ATl  = (const float*)d_in[8];
    const float* ALl  = (const float*)d_in[9];
    const float* Dsk  = (const float*)d_in[10];
    const float* Wo   = (const float*)d_in[11];
    const float* Wob  = (const float*)d_in[12];
    float* out = (float*)d_out;
    float* ws  = (float*)d_ws;

    hipLaunchKernelGGL(prep_k, dim3(612), dim3(256), 0, stream, Win, xpw, dtTw, dtLw, Wo, ws);
    hipLaunchKernelGGL(proj_k, dim3(512), dim3(256), 0, stream, x, Winb, dtTb, dtLb, ws);
    hipLaunchKernelGGL(scan_k, dim3(384), dim3(256), 0, stream, ATl, ALl, Dsk, ws);
    hipLaunchKernelGGL(out_k, dim3(512), dim3(256), 0, stream, Wob, ws, out);
}

// Round 2
// 203.889 us; speedup vs baseline: 1.2393x; 1.2393x over previous
//
#include <hip/hip_runtime.h>
#include <math.h>

#define DM 192
#define RNK 12
#define NS 16
#define NO2 432

// workspace float offsets
#define OFF_WINT   0u
#define OFF_WCOMB  36864u
#define OFF_WOT    119808u
#define OFF_FLAG   156672u
#define OFF_U      156688u            // row-major planes [bd][4096]; aliased as YG after repack
#define OFF_DT     1729552u           // = OFF_U + 384*4096
#define OFF_DL     3302416u           // = OFF_U + 768*4096
#define OFF_BC3    4875280u           // = OFF_U + 1152*4096 ; [b*48+comp][4096]
#define OFF_DIAG   5268496u           // 1248 packed-diag planes of 4096 floats
#define OFF_YG     OFF_U
// total 10,380,304 floats = 41.5 MB

__device__ __forceinline__ float gelu_f(float x){
    return 0.5f * x * (1.0f + erff(x * 0.70710678118654752f));
}
__device__ __forceinline__ float softplus_f(float x){
    return fmaxf(x, 0.0f) + log1pf(__expf(-fabsf(x)));
}
// packed anti-diagonal helpers: diag s has jmin=max(0,s-63), len=min(63,s)-jmin+1
__device__ __forceinline__ int diag_off(int s){
    return (s <= 64) ? ((s * (s + 1)) >> 1) : (2080 + (((s - 64) * (191 - s)) >> 1));
}

// ---------------- prep: transposes + combined dt-projection weight + A-structure flag ----------
__global__ __launch_bounds__(256) void prep_k(const float* __restrict__ Win,
                                              const float* __restrict__ xpw,
                                              const float* __restrict__ dtwT,
                                              const float* __restrict__ dtwL,
                                              const float* __restrict__ Wout,
                                              const float* __restrict__ ATl,
                                              const float* __restrict__ ALl,
                                              float* __restrict__ ws){
    if (blockIdx.x == 612){
        // verify A_log[d][n] == log(n+1) structure for both AT and AL
        __shared__ int okf;
        if (threadIdx.x == 0) okf = 1;
        __syncthreads();
        bool ok = true;
        for (int t = threadIdx.x; t < 6144; t += 256){
            const float* arr = (t < 3072) ? ATl : ALl;
            int e = (t < 3072) ? t : t - 3072;
            int n = e & 15;
            ok = ok && (fabsf(arr[e] - logf((float)(n + 1))) < 1e-5f);
        }
        if (!ok) atomicAnd(&okf, 0);
        __syncthreads();
        if (threadIdx.x == 0) ws[OFF_FLAG] = okf ? 1.0f : 0.0f;
        return;
    }
    int idx = blockIdx.x * 256 + threadIdx.x;
    if (idx < 36864){
        int c = idx / DM, d = idx % DM;
        ws[OFF_WINT + idx] = Win[d * DM + c];
    } else if (idx < 73728){
        int t = idx - 36864;
        int d = t / DM, c = t % DM;
        ws[OFF_WOT + t] = Wout[c * DM + d];
    } else if (idx < 156672){
        int t = idx - 73728;
        int c = t / NO2, o = t % NO2;
        float acc = 0.f;
        if (o < 192){
            #pragma unroll
            for (int r = 0; r < RNK; r++) acc += dtwT[o * RNK + r] * xpw[r * DM + c];
        } else if (o < 384){
            int d2 = o - 192;
            #pragma unroll
            for (int r = 0; r < RNK; r++) acc += dtwL[d2 * RNK + r] * xpw[(RNK + r) * DM + c];
        } else {
            acc = xpw[(2 * RNK + (o - 384)) * DM + c];
        }
        ws[OFF_WCOMB + t] = acc;
    }
}

// ---------------- fused projections ----------------
__global__ __launch_bounds__(256) void proj_k(const float* __restrict__ x,
                                              const float* __restrict__ inb,
                                              const float* __restrict__ dtTb,
                                              const float* __restrict__ dtLb,
                                              float* __restrict__ ws){
    __shared__ float x_t[16][196];
    __shared__ float u_t[16][196];
    const float* __restrict__ WinT = ws + OFF_WINT;
    const float* __restrict__ Wc   = ws + OFF_WCOMB;
    float* __restrict__ u_ws  = ws + OFF_U;
    float* __restrict__ dT_ws = ws + OFF_DT;
    float* __restrict__ dL_ws = ws + OFF_DL;

    const int p0 = blockIdx.x * 16;
    const int b = p0 >> 12;
    const int prel = p0 & 4095;
    const int tid = threadIdx.x;

    for (int i = tid; i < 16 * 192; i += 256){
        int pp = i / 192, c = i - pp * 192;
        x_t[pp][c] = x[(size_t)(p0 + pp) * 192 + c];
    }
    __syncthreads();

    if (tid < 192){
        const int td = tid % 48, tp = tid / 48;
        const int d0 = td * 4, pr = tp * 4;
        float acc[4][4];
        #pragma unroll
        for (int a = 0; a < 4; a++)
            #pragma unroll
            for (int bnk = 0; bnk < 4; bnk++) acc[a][bnk] = 0.f;
        for (int c = 0; c < 192; c += 4){
            float4 w0 = *(const float4*)&WinT[(c + 0) * 192 + d0];
            float4 w1 = *(const float4*)&WinT[(c + 1) * 192 + d0];
            float4 w2 = *(const float4*)&WinT[(c + 2) * 192 + d0];
            float4 w3 = *(const float4*)&WinT[(c + 3) * 192 + d0];
            #pragma unroll
            for (int pi = 0; pi < 4; pi++){
                float4 xv = *(const float4*)&x_t[pr + pi][c];
                acc[pi][0] = fmaf(xv.x, w0.x, fmaf(xv.y, w1.x, fmaf(xv.z, w2.x, fmaf(xv.w, w3.x, acc[pi][0]))));
                acc[pi][1] = fmaf(xv.x, w0.y, fmaf(xv.y, w1.y, fmaf(xv.z, w2.y, fmaf(xv.w, w3.y, acc[pi][1]))));
                acc[pi][2] = fmaf(xv.x, w0.z, fmaf(xv.y, w1.z, fmaf(xv.z, w2.z, fmaf(xv.w, w3.z, acc[pi][2]))));
                acc[pi][3] = fmaf(xv.x, w0.w, fmaf(xv.y, w1.w, fmaf(xv.z, w2.w, fmaf(xv.w, w3.w, acc[pi][3]))));
            }
        }
        float4 bv = *(const float4*)&inb[d0];
        float g[4][4];
        #pragma unroll
        for (int pi = 0; pi < 4; pi++){
            g[pi][0] = gelu_f(acc[pi][0] + bv.x);
            g[pi][1] = gelu_f(acc[pi][1] + bv.y);
            g[pi][2] = gelu_f(acc[pi][2] + bv.z);
            g[pi][3] = gelu_f(acc[pi][3] + bv.w);
        }
        #pragma unroll
        for (int pi = 0; pi < 4; pi++){
            *(float4*)&u_t[pr + pi][d0] = make_float4(g[pi][0], g[pi][1], g[pi][2], g[pi][3]);
        }
        #pragma unroll
        for (int dk = 0; dk < 4; dk++){
            *(float4*)&u_ws[(size_t)(b * 192 + d0 + dk) * 4096 + prel + pr] =
                make_float4(g[0][dk], g[1][dk], g[2][dk], g[3][dk]);
        }
    }
    __syncthreads();

    if (tid < 216){
        const int td = tid % 108, tp2 = tid / 108;
        const int o0 = td * 4, pr = tp2 * 8;
        float acc[8][4];
        #pragma unroll
        for (int a = 0; a < 8; a++)
            #pragma unroll
            for (int bnk = 0; bnk < 4; bnk++) acc[a][bnk] = 0.f;
        for (int c = 0; c < 192; c += 4){
            float4 w0 = *(const float4*)&Wc[(c + 0) * NO2 + o0];
            float4 w1 = *(const float4*)&Wc[(c + 1) * NO2 + o0];
            float4 w2 = *(const float4*)&Wc[(c + 2) * NO2 + o0];
            float4 w3 = *(const float4*)&Wc[(c + 3) * NO2 + o0];
            #pragma unroll
            for (int pi = 0; pi < 8; pi++){
                float4 xv = *(const float4*)&u_t[pr + pi][c];
                acc[pi][0] = fmaf(xv.x, w0.x, fmaf(xv.y, w1.x, fmaf(xv.z, w2.x, fmaf(xv.w, w3.x, acc[pi][0]))));
                acc[pi][1] = fmaf(xv.x, w0.y, fmaf(xv.y, w1.y, fmaf(xv.z, w2.y, fmaf(xv.w, w3.y, acc[pi][1]))));
                acc[pi][2] = fmaf(xv.x, w0.z, fmaf(xv.y, w1.z, fmaf(xv.z, w2.z, fmaf(xv.w, w3.z, acc[pi][2]))));
                acc[pi][3] = fmaf(xv.x, w0.w, fmaf(xv.y, w1.w, fmaf(xv.z, w2.w, fmaf(xv.w, w3.w, acc[pi][3]))));
            }
        }
        if (o0 < 192){
            #pragma unroll
            for (int ok = 0; ok < 4; ok++){
                int d = o0 + ok;
                float bb = dtTb[d];
                float v[8];
                #pragma unroll
                for (int pi = 0; pi < 8; pi++) v[pi] = softplus_f(acc[pi][ok] + bb);
                float* dst = &dT_ws[(size_t)(b * 192 + d) * 4096 + prel + pr];
                *(float4*)&dst[0] = make_float4(v[0], v[1], v[2], v[3]);
                *(float4*)&dst[4] = make_float4(v[4], v[5], v[6], v[7]);
            }
        } else if (o0 < 384){
            #pragma unroll
            for (int ok = 0; ok < 4; ok++){
                int d = o0 - 192 + ok;
                float bb = dtLb[d];
                float v[8];
                #pragma unroll
                for (int pi = 0; pi < 8; pi++) v[pi] = softplus_f(acc[pi][ok] + bb);
                float* dst = &dL_ws[(size_t)(b * 192 + d) * 4096 + prel + pr];
                *(float4*)&dst[0] = make_float4(v[0], v[1], v[2], v[3]);
                *(float4*)&dst[4] = make_float4(v[4], v[5], v[6], v[7]);
            }
        } else {
            int col0 = o0 - 384;   // 0..44 step 4 ; comp = col0+ok in [0,48)
            #pragma unroll
            for (int ok = 0; ok < 4; ok++){
                float* dst = &ws[OFF_BC3 + (size_t)(b * 48 + col0 + ok) * 4096 + prel + pr];
                *(float4*)&dst[0] = make_float4(acc[0][ok], acc[1][ok], acc[2][ok], acc[3][ok]);
                *(float4*)&dst[4] = make_float4(acc[4][ok], acc[5][ok], acc[6][ok], acc[7][ok]);
            }
        }
    }
}

// ---------------- repack: row-major 64x64 plane -> packed anti-diagonal plane ----------------
__global__ __launch_bounds__(256) void repack_k(float* __restrict__ ws){
    __shared__ float ldsf[4096];
    const int p = blockIdx.x;                   // 0..1247
    const float4* __restrict__ src4 = (const float4*)(ws + OFF_U + (size_t)p * 4096);
    float* __restrict__ dst = ws + OFF_DIAG + (size_t)p * 4096;
    const int tid = threadIdx.x;
    float4* lds4 = (float4*)ldsf;
    #pragma unroll
    for (int k = 0; k < 4; k++) lds4[tid + k * 256] = src4[tid + k * 256];
    __syncthreads();
    const int wv = tid >> 6, j2 = tid & 63;
    for (int s = wv; s < 127; s += 4){
        const int jmin = (s > 63) ? (s - 63) : 0;
        const int jmax = (s < 63) ? s : 63;
        const int len = jmax - jmin + 1;
        if (j2 < len){
            const int j = jmin + j2;
            dst[diag_off(s) + j2] = ldsf[(s - j) * 64 + j];
        }
    }
}

// ---------------- diagonal wavefront scan: block per (b,d), 4 free-running waves over n ------
#define LOADSET(pfx, sv) do {                                                   \
    int sc_ = (sv) < 126 ? (sv) : 126;                                          \
    int jmin_ = (sc_ > 63) ? (sc_ - 63) : 0;                                    \
    int q_ = diag_off(sc_) - jmin_ + j;                                         \
    if (q_ > 4095) q_ = 4095;                                                   \
    pfx##_dT = pdT[q_]; pfx##_dL = pdL[q_]; pfx##_u = pu[q_];                   \
    pfx##_b0 = pBT[q_];          pfx##_b1 = pBT[4096 + q_];                     \
    pfx##_b2 = pBT[8192 + q_];   pfx##_b3 = pBT[12288 + q_];                    \
    pfx##_l0 = pBL[q_];          pfx##_l1 = pBL[4096 + q_];                     \
    pfx##_l2 = pBL[8192 + q_];   pfx##_l3 = pBL[12288 + q_];                    \
    pfx##_c0 = pC[q_];           pfx##_c1 = pC[4096 + q_];                      \
    pfx##_c2 = pC[8192 + q_];    pfx##_c3 = pC[12288 + q_];                     \
} while (0)

#define STEP(pfx, sv) do {                                                      \
    const float dT_ = pfx##_dT, dL_ = pfx##_dL, u_ = pfx##_u;                   \
    const float bt0_ = pfx##_b0, bt1_ = pfx##_b1, bt2_ = pfx##_b2, bt3_ = pfx##_b3; \
    const float bl0_ = pfx##_l0, bl1_ = pfx##_l1, bl2_ = pfx##_l2, bl3_ = pfx##_l3; \
    const float cc0_ = pfx##_c0, cc1_ = pfx##_c1, cc2_ = pfx##_c2, cc3_ = pfx##_c3; \
    LOADSET(pfx, (sv) + 2);                                                     \
    float da0_, da1_, da2_, da3_, dl0_, dl1_, dl2_, dl3_;                       \
    if (sflag){                                                                 \
        const float E_ = __expf(-dT_);                                          \
        da0_ = __expf(nA1 * dT_); da1_ = da0_ * E_; da2_ = da1_ * E_; da3_ = da2_ * E_; \
        const float F_ = __expf(-dL_);                                          \
        dl0_ = __expf(nA1 * dL_); dl1_ = dl0_ * F_; dl2_ = dl1_ * F_; dl3_ = dl2_ * F_; \
    } else {                                                                    \
        da0_ = __expf(dT_ * ATr[0]); da1_ = __expf(dT_ * ATr[1]);               \
        da2_ = __expf(dT_ * ATr[2]); da3_ = __expf(dT_ * ATr[3]);               \
        dl0_ = __expf(dL_ * ALr[0]); dl1_ = __expf(dL_ * ALr[1]);               \
        dl2_ = __expf(dL_ * ALr[2]); dl3_ = __expf(dL_ * ALr[3]);               \
    }                                                                           \
    const int ic_ = (sv) - j;                                                   \
    const bool act_ = ((unsigned)ic_) < 64u;                                    \
    const float udT_ = u_ * dT_, udL_ = u_ * dL_;                               \
    float y_ = 0.f;                                                             \
    { float hl = __shfl_up(h0, 1u, 64); hl = (j == 0) ? 0.f : hl;               \
      float hn = fmaf(da0_, h0, fmaf(dl0_, hl, fmaf(udT_, bt0_, udL_ * bl0_))); \
      h0 = act_ ? hn : h0; y_ = fmaf(hn, cc0_, y_); }                           \
    { float hl = __shfl_up(h1, 1u, 64); hl = (j == 0) ? 0.f : hl;               \
      float hn = fmaf(da1_, h1, fmaf(dl1_, hl, fmaf(udT_, bt1_, udL_ * bl1_))); \
      h1 = act_ ? hn : h1; y_ = fmaf(hn, cc1_, y_); }                           \
    { float hl = __shfl_up(h2, 1u, 64); hl = (j == 0) ? 0.f : hl;               \
      float hn = fmaf(da2_, h2, fmaf(dl2_, hl, fmaf(udT_, bt2_, udL_ * bl2_))); \
      h2 = act_ ? hn : h2; y_ = fmaf(hn, cc2_, y_); }                           \
    { float hl = __shfl_up(h3, 1u, 64); hl = (j == 0) ? 0.f : hl;               \
      float hn = fmaf(da3_, h3, fmaf(dl3_, hl, fmaf(udT_, bt3_, udL_ * bl3_))); \
      h3 = act_ ? hn : h3; y_ = fmaf(hn, cc3_, y_); }                           \
    if (act_) atomicAdd(&ylds[ic_ * 64 + j], y_);                               \
} while (0)

__global__ __launch_bounds__(256) void scan_k(const float* __restrict__ ATl,
                                              const float* __restrict__ ALl,
                                              const float* __restrict__ Dskp,
                                              float* __restrict__ ws){
    __shared__ float ylds[4096];
    const int bd = blockIdx.x;
    const int b = bd / 192, d = bd - b * 192;
    const int tid = threadIdx.x;
    const int wv = tid >> 6, j = tid & 63;
    const int n0 = wv << 2;

    #pragma unroll
    for (int k = 0; k < 16; k++) ylds[tid + k * 256] = 0.f;
    __syncthreads();

    const float* __restrict__ pu  = ws + OFF_DIAG + (size_t)bd * 4096;
    const float* __restrict__ pdT = ws + OFF_DIAG + (size_t)(384 + bd) * 4096;
    const float* __restrict__ pdL = ws + OFF_DIAG + (size_t)(768 + bd) * 4096;
    const float* __restrict__ pbc = ws + OFF_DIAG + (size_t)(1152 + b * 48) * 4096;
    const float* __restrict__ pBT = pbc + (size_t)n0 * 4096;
    const float* __restrict__ pBL = pbc + (size_t)(16 + n0) * 4096;
    const float* __restrict__ pC  = pbc + (size_t)(32 + n0) * 4096;

    const bool sflag = (ws[OFF_FLAG] > 0.5f);
    const float nA1 = -(float)(n0 + 1);
    float ATr[4], ALr[4];
    #pragma unroll
    for (int k = 0; k < 4; k++){
        ATr[k] = -expf(ATl[d * NS + n0 + k]);
        ALr[k] = -expf(ALl[d * NS + n0 + k]);
    }
    float h0 = 0.f, h1 = 0.f, h2 = 0.f, h3 = 0.f;

    float a_dT, a_dL, a_u, a_b0, a_b1, a_b2, a_b3, a_l0, a_l1, a_l2, a_l3, a_c0, a_c1, a_c2, a_c3;
    float b_dT, b_dL, b_u, b_b0, b_b1, b_b2, b_b3, b_l0, b_l1, b_l2, b_l3, b_c0, b_c1, b_c2, b_c3;
    LOADSET(a, 0);
    LOADSET(b, 1);

    for (int s = 0; s < 128; s += 2){
        STEP(a, s);
        STEP(b, s + 1);
    }

    __syncthreads();
    const float Dsk = Dskp[d];
    float* __restrict__ yg = ws + OFF_YG + (size_t)bd * 4096;
    for (int idx = tid; idx < 4096; idx += 256){
        const int i = idx >> 6, jj = idx & 63;
        const int s = i + jj;
        const int jmin = (s > 63) ? (s - 63) : 0;
        const float uv = pu[diag_off(s) + jj - jmin];
        yg[idx] = gelu_f(ylds[idx] + uv * Dsk);
    }
}

// ---------------- out projection ----------------
__global__ __launch_bounds__(256) void out_k(const float* __restrict__ Wob,
                                             float* __restrict__ ws,
                                             float* __restrict__ out){
    __shared__ float yg_t[16][196];
    const float* __restrict__ WoT = ws + OFF_WOT;
    const float* __restrict__ yg  = ws + OFF_YG;
    const int p0 = blockIdx.x * 16;
    const int b = p0 >> 12;
    const int prel = p0 & 4095;
    const int tid = threadIdx.x;

    if (tid < 192){
        const float* src = yg + (size_t)(b * 192 + tid) * 4096 + prel;
        #pragma unroll
        for (int q = 0; q < 4; q++){
            float4 v = *(const float4*)&src[q * 4];
            yg_t[q * 4 + 0][tid] = v.x;
            yg_t[q * 4 + 1][tid] = v.y;
            yg_t[q * 4 + 2][tid] = v.z;
            yg_t[q * 4 + 3][tid] = v.w;
        }
    }
    __syncthreads();

    if (tid < 192){
        const int td = tid % 48, tp = tid / 48;
        const int c0 = td * 4, pr = tp * 4;
        float acc[4][4];
        #pragma unroll
        for (int a = 0; a < 4; a++)
            #pragma unroll
            for (int bnk = 0; bnk < 4; bnk++) acc[a][bnk] = 0.f;
        for (int dd = 0; dd < 192; dd += 4){
            float4 w0 = *(const float4*)&WoT[(dd + 0) * 192 + c0];
            float4 w1 = *(const float4*)&WoT[(dd + 1) * 192 + c0];
            float4 w2 = *(const float4*)&WoT[(dd + 2) * 192 + c0];
            float4 w3 = *(const float4*)&WoT[(dd + 3) * 192 + c0];
            #pragma unroll
            for (int pi = 0; pi < 4; pi++){
                float4 xv = *(const float4*)&yg_t[pr + pi][dd];
                acc[pi][0] = fmaf(xv.x, w0.x, fmaf(xv.y, w1.x, fmaf(xv.z, w2.x, fmaf(xv.w, w3.x, acc[pi][0]))));
                acc[pi][1] = fmaf(xv.x, w0.y, fmaf(xv.y, w1.y, fmaf(xv.z, w2.y, fmaf(xv.w, w3.y, acc[pi][1]))));
                acc[pi][2] = fmaf(xv.x, w0.z, fmaf(xv.y, w1.z, fmaf(xv.z, w2.z, fmaf(xv.w, w3.z, acc[pi][2]))));
                acc[pi][3] = fmaf(xv.x, w0.w, fmaf(xv.y, w1.w, fmaf(xv.z, w2.w, fmaf(xv.w, w3.w, acc[pi][3]))));
            }
        }
        float4 bv = *(const float4*)&Wob[c0];
        #pragma unroll
        for (int pi = 0; pi < 4; pi++){
            float4 ov = make_float4(acc[pi][0] + bv.x, acc[pi][1] + bv.y,
                                    acc[pi][2] + bv.z, acc[pi][3] + bv.w);
            *(float4*)&out[(size_t)(p0 + pr + pi) * 192 + c0] = ov;
        }
    }
}

extern "C" void kernel_launch(void* const* d_in, const int* in_sizes, int n_in,
                              void* d_out, int out_size, void* d_ws, size_t ws_size,
                              hipStream_t stream) {
    const float* x    = (const float*)d_in[0];
    const float* Win  = (const float*)d_in[1];
    const float* Winb = (const float*)d_in[2];
    const float* xpw  = (const float*)d_in[3];
    const float* dtTw = (const float*)d_in[4];
    const float* dtTb = (const float*)d_in[5];
    const float* dtLw = (const float*)d_in[6];
    const float* dtLb = (const float*)d_in[7];
    const float* ATl  = (const float*)d_in[8];
    const float* ALl  = (const float*)d_in[9];
    const float* Dsk  = (const float*)d_in[10];
    const float* Wo   = (const float*)d_in[11];
    const float* Wob  = (const float*)d_in[12];
    float* out = (float*)d_out;
    float* ws  = (float*)d_ws;

    hipLaunchKernelGGL(prep_k, dim3(613), dim3(256), 0, stream, Win, xpw, dtTw, dtLw, Wo, ATl, ALl, ws);
    hipLaunchKernelGGL(proj_k, dim3(512), dim3(256), 0, stream, x, Winb, dtTb, dtLb, ws);
    hipLaunchKernelGGL(repack_k, dim3(1248), dim3(256), 0, stream, ws);
    hipLaunchKernelGGL(scan_k, dim3(384), dim3(256), 0, stream, ATl, ALl, Dsk, ws);
    hipLaunchKernelGGL(out_k, dim3(512), dim3(256), 0, stream, Wob, ws, out);
}

// Round 3
// 187.662 us; speedup vs baseline: 1.3464x; 1.0865x over previous
//
#include <hip/hip_runtime.h>
#include <math.h>

#define DM 192
#define RNK 12
#define NS 16
#define NO2 432

// workspace float offsets
#define OFF_WINT   0u
#define OFF_WCOMB  36864u
#define OFF_WOT    119808u
#define OFF_FLAG   156672u
#define OFF_U      156688u            // row-major planes [bd][4096]; partial-y(0) after repack
#define OFF_DT     1729552u           // = OFF_U + 384*4096 ; YG after scan
#define OFF_DL     3302416u           // = OFF_U + 768*4096 ; partial-y(1) after repack
#define OFF_BC3    4875280u           // = OFF_U + 1152*4096 ; float4-interleaved [b*12+grp][4096][4]
#define OFF_DIAG   5268496u           // 1152 scalar diag planes + 24 float4 diag planes
#define OFF_BC4D   (OFF_DIAG + 1152u*4096u)
// total 10,380,304 floats = 41.5 MB (unchanged from round 2)

__device__ __forceinline__ float gelu_f(float x){
    return 0.5f * x * (1.0f + erff(x * 0.70710678118654752f));
}
__device__ __forceinline__ float softplus_f(float x){
    return fmaxf(x, 0.0f) + log1pf(__expf(-fabsf(x)));
}
// packed anti-diagonal: diag s has jmin=max(0,s-63), len=min(63,s)-jmin+1, sum len = 4096
__device__ __forceinline__ int diag_off(int s){
    return (s <= 64) ? ((s * (s + 1)) >> 1) : (2080 + (((s - 64) * (191 - s)) >> 1));
}

// ---------------- prep ----------------
__global__ __launch_bounds__(256) void prep_k(const float* __restrict__ Win,
                                              const float* __restrict__ xpw,
                                              const float* __restrict__ dtwT,
                                              const float* __restrict__ dtwL,
                                              const float* __restrict__ Wout,
                                              const float* __restrict__ ATl,
                                              const float* __restrict__ ALl,
                                              float* __restrict__ ws){
    if (blockIdx.x == 612){
        __shared__ int okf;
        if (threadIdx.x == 0) okf = 1;
        __syncthreads();
        bool ok = true;
        for (int t = threadIdx.x; t < 6144; t += 256){
            const float* arr = (t < 3072) ? ATl : ALl;
            int e = (t < 3072) ? t : t - 3072;
            int n = e & 15;
            ok = ok && (fabsf(arr[e] - logf((float)(n + 1))) < 1e-5f);
        }
        if (!ok) atomicAnd(&okf, 0);
        __syncthreads();
        if (threadIdx.x == 0) ws[OFF_FLAG] = okf ? 1.0f : 0.0f;
        return;
    }
    int idx = blockIdx.x * 256 + threadIdx.x;
    if (idx < 36864){
        int c = idx / DM, d = idx % DM;
        ws[OFF_WINT + idx] = Win[d * DM + c];
    } else if (idx < 73728){
        int t = idx - 36864;
        int d = t / DM, c = t % DM;
        ws[OFF_WOT + t] = Wout[c * DM + d];
    } else if (idx < 156672){
        int t = idx - 73728;
        int c = t / NO2, o = t % NO2;
        float acc = 0.f;
        if (o < 192){
            #pragma unroll
            for (int r = 0; r < RNK; r++) acc += dtwT[o * RNK + r] * xpw[r * DM + c];
        } else if (o < 384){
            int d2 = o - 192;
            #pragma unroll
            for (int r = 0; r < RNK; r++) acc += dtwL[d2 * RNK + r] * xpw[(RNK + r) * DM + c];
        } else {
            acc = xpw[(2 * RNK + (o - 384)) * DM + c];
        }
        ws[OFF_WCOMB + t] = acc;
    }
}

// ---------------- fused projections ----------------
__global__ __launch_bounds__(256) void proj_k(const float* __restrict__ x,
                                              const float* __restrict__ inb,
                                              const float* __restrict__ dtTb,
                                              const float* __restrict__ dtLb,
                                              float* __restrict__ ws){
    __shared__ float x_t[16][196];
    __shared__ float u_t[16][196];
    const float* __restrict__ WinT = ws + OFF_WINT;
    const float* __restrict__ Wc   = ws + OFF_WCOMB;
    float* __restrict__ u_ws  = ws + OFF_U;
    float* __restrict__ dT_ws = ws + OFF_DT;
    float* __restrict__ dL_ws = ws + OFF_DL;

    const int p0 = blockIdx.x * 16;
    const int b = p0 >> 12;
    const int prel = p0 & 4095;
    const int tid = threadIdx.x;

    for (int i = tid; i < 16 * 192; i += 256){
        int pp = i / 192, c = i - pp * 192;
        x_t[pp][c] = x[(size_t)(p0 + pp) * 192 + c];
    }
    __syncthreads();

    if (tid < 192){
        const int td = tid % 48, tp = tid / 48;
        const int d0 = td * 4, pr = tp * 4;
        float acc[4][4];
        #pragma unroll
        for (int a = 0; a < 4; a++)
            #pragma unroll
            for (int bnk = 0; bnk < 4; bnk++) acc[a][bnk] = 0.f;
        for (int c = 0; c < 192; c += 4){
            float4 w0 = *(const float4*)&WinT[(c + 0) * 192 + d0];
            float4 w1 = *(const float4*)&WinT[(c + 1) * 192 + d0];
            float4 w2 = *(const float4*)&WinT[(c + 2) * 192 + d0];
            float4 w3 = *(const float4*)&WinT[(c + 3) * 192 + d0];
            #pragma unroll
            for (int pi = 0; pi < 4; pi++){
                float4 xv = *(const float4*)&x_t[pr + pi][c];
                acc[pi][0] = fmaf(xv.x, w0.x, fmaf(xv.y, w1.x, fmaf(xv.z, w2.x, fmaf(xv.w, w3.x, acc[pi][0]))));
                acc[pi][1] = fmaf(xv.x, w0.y, fmaf(xv.y, w1.y, fmaf(xv.z, w2.y, fmaf(xv.w, w3.y, acc[pi][1]))));
                acc[pi][2] = fmaf(xv.x, w0.z, fmaf(xv.y, w1.z, fmaf(xv.z, w2.z, fmaf(xv.w, w3.z, acc[pi][2]))));
                acc[pi][3] = fmaf(xv.x, w0.w, fmaf(xv.y, w1.w, fmaf(xv.z, w2.w, fmaf(xv.w, w3.w, acc[pi][3]))));
            }
        }
        float4 bv = *(const float4*)&inb[d0];
        float g[4][4];
        #pragma unroll
        for (int pi = 0; pi < 4; pi++){
            g[pi][0] = gelu_f(acc[pi][0] + bv.x);
            g[pi][1] = gelu_f(acc[pi][1] + bv.y);
            g[pi][2] = gelu_f(acc[pi][2] + bv.z);
            g[pi][3] = gelu_f(acc[pi][3] + bv.w);
        }
        #pragma unroll
        for (int pi = 0; pi < 4; pi++){
            *(float4*)&u_t[pr + pi][d0] = make_float4(g[pi][0], g[pi][1], g[pi][2], g[pi][3]);
        }
        #pragma unroll
        for (int dk = 0; dk < 4; dk++){
            *(float4*)&u_ws[(size_t)(b * 192 + d0 + dk) * 4096 + prel + pr] =
                make_float4(g[0][dk], g[1][dk], g[2][dk], g[3][dk]);
        }
    }
    __syncthreads();

    if (tid < 216){
        const int td = tid % 108, tp2 = tid / 108;
        const int o0 = td * 4, pr = tp2 * 8;
        float acc[8][4];
        #pragma unroll
        for (int a = 0; a < 8; a++)
            #pragma unroll
            for (int bnk = 0; bnk < 4; bnk++) acc[a][bnk] = 0.f;
        for (int c = 0; c < 192; c += 4){
            float4 w0 = *(const float4*)&Wc[(c + 0) * NO2 + o0];
            float4 w1 = *(const float4*)&Wc[(c + 1) * NO2 + o0];
            float4 w2 = *(const float4*)&Wc[(c + 2) * NO2 + o0];
            float4 w3 = *(const float4*)&Wc[(c + 3) * NO2 + o0];
            #pragma unroll
            for (int pi = 0; pi < 8; pi++){
                float4 xv = *(const float4*)&u_t[pr + pi][c];
                acc[pi][0] = fmaf(xv.x, w0.x, fmaf(xv.y, w1.x, fmaf(xv.z, w2.x, fmaf(xv.w, w3.x, acc[pi][0]))));
                acc[pi][1] = fmaf(xv.x, w0.y, fmaf(xv.y, w1.y, fmaf(xv.z, w2.y, fmaf(xv.w, w3.y, acc[pi][1]))));
                acc[pi][2] = fmaf(xv.x, w0.z, fmaf(xv.y, w1.z, fmaf(xv.z, w2.z, fmaf(xv.w, w3.z, acc[pi][2]))));
                acc[pi][3] = fmaf(xv.x, w0.w, fmaf(xv.y, w1.w, fmaf(xv.z, w2.w, fmaf(xv.w, w3.w, acc[pi][3]))));
            }
        }
        if (o0 < 192){
            #pragma unroll
            for (int ok = 0; ok < 4; ok++){
                int d = o0 + ok;
                float bb = dtTb[d];
                float v[8];
                #pragma unroll
                for (int pi = 0; pi < 8; pi++) v[pi] = softplus_f(acc[pi][ok] + bb);
                float* dst = &dT_ws[(size_t)(b * 192 + d) * 4096 + prel + pr];
                *(float4*)&dst[0] = make_float4(v[0], v[1], v[2], v[3]);
                *(float4*)&dst[4] = make_float4(v[4], v[5], v[6], v[7]);
            }
        } else if (o0 < 384){
            #pragma unroll
            for (int ok = 0; ok < 4; ok++){
                int d = o0 - 192 + ok;
                float bb = dtLb[d];
                float v[8];
                #pragma unroll
                for (int pi = 0; pi < 8; pi++) v[pi] = softplus_f(acc[pi][ok] + bb);
                float* dst = &dL_ws[(size_t)(b * 192 + d) * 4096 + prel + pr];
                *(float4*)&dst[0] = make_float4(v[0], v[1], v[2], v[3]);
                *(float4*)&dst[4] = make_float4(v[4], v[5], v[6], v[7]);
            }
        } else {
            // B/C states, float4-interleaved: plane (b*12 + c4*4 + ng), cell = float4 of states 4ng..4ng+3
            const int col0 = o0 - 384;            // 0..44 step 4
            const int c4 = col0 >> 4;             // 0=BT 1=BL 2=C
            const int ng = (col0 >> 2) & 3;       // state group
            float4* dst = (float4*)(ws + OFF_BC3) + (size_t)(b * 12 + c4 * 4 + ng) * 4096 + prel + pr;
            #pragma unroll
            for (int pi = 0; pi < 8; pi++)
                dst[pi] = make_float4(acc[pi][0], acc[pi][1], acc[pi][2], acc[pi][3]);
        }
    }
}

// ---------------- repack scalar planes (u,dT,dL) row-major -> packed diag ----------------
__global__ __launch_bounds__(256) void repack_k(float* __restrict__ ws){
    __shared__ float ldsf[4096];
    const int p = blockIdx.x;                   // 0..1151
    const float4* __restrict__ src4 = (const float4*)(ws + OFF_U + (size_t)p * 4096);
    float* __restrict__ dst = ws + OFF_DIAG + (size_t)p * 4096;
    const int tid = threadIdx.x;
    float4* lds4 = (float4*)ldsf;
    #pragma unroll
    for (int k = 0; k < 4; k++) lds4[tid + k * 256] = src4[tid + k * 256];
    __syncthreads();
    const int wv = tid >> 6, j2 = tid & 63;
    for (int s = wv; s < 127; s += 4){
        const int jmin = (s > 63) ? (s - 63) : 0;
        const int jmax = (s < 63) ? s : 63;
        const int len = jmax - jmin + 1;
        if (j2 < len){
            const int j = jmin + j2;
            dst[diag_off(s) + j2] = ldsf[(s - j) * 64 + j];
        }
    }
}

// ---------------- repack BC float4 planes row-major -> packed diag ----------------
__global__ __launch_bounds__(256) void repackbc_k(float* __restrict__ ws){
    __shared__ float4 l4[4096];                 // 64 KB
    const int p = blockIdx.x;                   // 0..23
    const float4* __restrict__ src = (const float4*)(ws + OFF_BC3) + (size_t)p * 4096;
    float4* __restrict__ dst = (float4*)(ws + OFF_BC4D) + (size_t)p * 4096;
    const int tid = threadIdx.x;
    #pragma unroll
    for (int k = 0; k < 16; k++) l4[tid + k * 256] = src[tid + k * 256];
    __syncthreads();
    const int wv = tid >> 6, j2 = tid & 63;
    for (int s = wv; s < 127; s += 4){
        const int jmin = (s > 63) ? (s - 63) : 0;
        const int jmax = (s < 63) ? s : 63;
        const int len = jmax - jmin + 1;
        if (j2 < len){
            const int j = jmin + j2;
            dst[diag_off(s) + j2] = l4[(s - j) * 64 + j];
        }
    }
}

// ---------------- diagonal wavefront scan ----------------
// 768 blocks x 128 threads: block = (bd, half); wave wv handles states n0 = half*8+wv*4.
// Per wave: depth-3 prefetch, 6 loads/step (3 scalar + 3 float4), private LDS y plane.
#define LOADSET(pfx, sv) do {                                                   \
    const int sv_ = (sv);                                                       \
    const int sc_ = sv_ < 126 ? sv_ : 126;                                      \
    const int jmin_ = (sc_ > 63) ? (sc_ - 63) : 0;                              \
    pfx##_q = diag_off(sc_) - jmin_ + j;                                        \
    pfx##_dT = pdT[pfx##_q]; pfx##_dL = pdL[pfx##_q]; pfx##_u = pu[pfx##_q];    \
    pfx##_bt = pBT[pfx##_q]; pfx##_bl = pBL[pfx##_q]; pfx##_cc = pC[pfx##_q];   \
} while (0)

#define STEP(pfx, sv) do {                                                      \
    const float dT_ = pfx##_dT, dL_ = pfx##_dL, u_ = pfx##_u;                   \
    const float bt_[4] = {pfx##_bt.x, pfx##_bt.y, pfx##_bt.z, pfx##_bt.w};      \
    const float bl_[4] = {pfx##_bl.x, pfx##_bl.y, pfx##_bl.z, pfx##_bl.w};      \
    const float cc_[4] = {pfx##_cc.x, pfx##_cc.y, pfx##_cc.z, pfx##_cc.w};      \
    const int q_ = pfx##_q;                                                     \
    LOADSET(pfx, (sv) + 3);                                                     \
    float da_[4], dl_[4];                                                       \
    if (sflag){                                                                 \
        const float E_ = __expf(-dT_), F_ = __expf(-dL_);                       \
        da_[0] = __expf(nA1 * dT_); dl_[0] = __expf(nA1 * dL_);                 \
        da_[1] = da_[0] * E_; da_[2] = da_[1] * E_; da_[3] = da_[2] * E_;       \
        dl_[1] = dl_[0] * F_; dl_[2] = dl_[1] * F_; dl_[3] = dl_[2] * F_;       \
    } else {                                                                    \
        da_[0] = __expf(dT_ * ATr[0]); da_[1] = __expf(dT_ * ATr[1]);           \
        da_[2] = __expf(dT_ * ATr[2]); da_[3] = __expf(dT_ * ATr[3]);           \
        dl_[0] = __expf(dL_ * ALr[0]); dl_[1] = __expf(dL_ * ALr[1]);           \
        dl_[2] = __expf(dL_ * ALr[2]); dl_[3] = __expf(dL_ * ALr[3]);           \
    }                                                                           \
    const int ic_ = (sv) - j;                                                   \
    const bool act_ = ((unsigned)ic_) < 64u;                                    \
    const float udT_ = u_ * dT_, udL_ = u_ * dL_;                               \
    float y_ = 0.f;                                                             \
    _Pragma("unroll")                                                           \
    for (int k = 0; k < 4; k++){                                                \
        float hl_ = __shfl_up(h[k], 1u, 64);                                    \
        hl_ = (j == 0) ? 0.f : hl_;                                             \
        float hn_ = fmaf(da_[k], h[k], fmaf(dl_[k], hl_, fmaf(udT_, bt_[k], udL_ * bl_[k]))); \
        h[k] = act_ ? hn_ : h[k];                                               \
        y_ = fmaf(hn_, cc_[k], y_);                                             \
    }                                                                           \
    if (act_) ylds[wv][q_] = y_;                                                \
} while (0)

__global__ __launch_bounds__(128) void scan_k(const float* __restrict__ ATl,
                                              const float* __restrict__ ALl,
                                              float* __restrict__ ws){
    __shared__ float ylds[2][4096];             // 32 KB
    const int bx = blockIdx.x;
    const int bd = bx >> 1, half = bx & 1;
    const int b = bd / 192, d = bd - b * 192;
    const int tid = threadIdx.x;
    const int wv = tid >> 6, j = tid & 63;
    const int n0 = half * 8 + wv * 4;
    const int ng = half * 2 + wv;

    const float* __restrict__ pu  = ws + OFF_DIAG + (size_t)bd * 4096;
    const float* __restrict__ pdT = ws + OFF_DIAG + (size_t)(384 + bd) * 4096;
    const float* __restrict__ pdL = ws + OFF_DIAG + (size_t)(768 + bd) * 4096;
    const float4* __restrict__ bc4 = (const float4*)(ws + OFF_BC4D) + (size_t)(b * 12) * 4096;
    const float4* __restrict__ pBT = bc4 + (size_t)(0 + ng) * 4096;
    const float4* __restrict__ pBL = bc4 + (size_t)(4 + ng) * 4096;
    const float4* __restrict__ pC  = bc4 + (size_t)(8 + ng) * 4096;
    float* __restrict__ pY = ws + (half ? OFF_DL : OFF_U) + (size_t)bd * 4096;

    const bool sflag = (ws[OFF_FLAG] > 0.5f);
    const float nA1 = -(float)(n0 + 1);
    float ATr[4], ALr[4];
    if (!sflag){
        #pragma unroll
        for (int k = 0; k < 4; k++){
            ATr[k] = -expf(ATl[d * NS + n0 + k]);
            ALr[k] = -expf(ALl[d * NS + n0 + k]);
        }
    } else {
        #pragma unroll
        for (int k = 0; k < 4; k++){ ATr[k] = 0.f; ALr[k] = 0.f; }
    }
    float h[4] = {0.f, 0.f, 0.f, 0.f};

    int a_q, b_q, c_q;
    float a_dT, a_dL, a_u; float4 a_bt, a_bl, a_cc;
    float b_dT, b_dL, b_u; float4 b_bt, b_bl, b_cc;
    float c_dT, c_dL, c_u; float4 c_bt, c_bl, c_cc;
    LOADSET(a, 0);
    LOADSET(b, 1);
    LOADSET(c, 2);

    for (int s = 0; s < 129; s += 3){
        STEP(a, s);
        STEP(b, s + 1);
        STEP(c, s + 2);
    }

    __syncthreads();
    for (int idx = tid; idx < 4096; idx += 128)
        pY[idx] = ylds[0][idx] + ylds[1][idx];
}

// ---------------- y-sum + gelu + diag->row ----------------
__global__ __launch_bounds__(256) void ysum_k(const float* __restrict__ Dskp,
                                              float* __restrict__ ws){
    __shared__ float yl[4096];
    const int bd = blockIdx.x;
    const int d = bd % 192;
    const int tid = threadIdx.x;
    const float* __restrict__ p0 = ws + OFF_U  + (size_t)bd * 4096;
    const float* __restrict__ p1 = ws + OFF_DL + (size_t)bd * 4096;
    const float* __restrict__ pu = ws + OFF_DIAG + (size_t)bd * 4096;
    float* __restrict__ yg = ws + OFF_DT + (size_t)bd * 4096;
    const float Dsk = Dskp[d];
    #pragma unroll
    for (int k = 0; k < 16; k++){
        const int idx = tid + k * 256;
        yl[idx] = gelu_f(p0[idx] + p1[idx] + pu[idx] * Dsk);
    }
    __syncthreads();
    #pragma unroll
    for (int k = 0; k < 16; k++){
        const int idx = tid + k * 256;
        const int i = idx >> 6, jj = idx & 63;
        const int s = i + jj;
        const int jmin = (s > 63) ? (s - 63) : 0;
        yg[idx] = yl[diag_off(s) + jj - jmin];
    }
}

// ---------------- out projection ----------------
__global__ __launch_bounds__(256) void out_k(const float* __restrict__ Wob,
                                             float* __restrict__ ws,
                                             float* __restrict__ out){
    __shared__ float yg_t[16][196];
    const float* __restrict__ WoT = ws + OFF_WOT;
    const float* __restrict__ yg  = ws + OFF_DT;
    const int p0 = blockIdx.x * 16;
    const int b = p0 >> 12;
    const int prel = p0 & 4095;
    const int tid = threadIdx.x;

    if (tid < 192){
        const float* src = yg + (size_t)(b * 192 + tid) * 4096 + prel;
        #pragma unroll
        for (int q = 0; q < 4; q++){
            float4 v = *(const float4*)&src[q * 4];
            yg_t[q * 4 + 0][tid] = v.x;
            yg_t[q * 4 + 1][tid] = v.y;
            yg_t[q * 4 + 2][tid] = v.z;
            yg_t[q * 4 + 3][tid] = v.w;
        }
    }
    __syncthreads();

    if (tid < 192){
        const int td = tid % 48, tp = tid / 48;
        const int c0 = td * 4, pr = tp * 4;
        float acc[4][4];
        #pragma unroll
        for (int a = 0; a < 4; a++)
            #pragma unroll
            for (int bnk = 0; bnk < 4; bnk++) acc[a][bnk] = 0.f;
        for (int dd = 0; dd < 192; dd += 4){
            float4 w0 = *(const float4*)&WoT[(dd + 0) * 192 + c0];
            float4 w1 = *(const float4*)&WoT[(dd + 1) * 192 + c0];
            float4 w2 = *(const float4*)&WoT[(dd + 2) * 192 + c0];
            float4 w3 = *(const float4*)&WoT[(dd + 3) * 192 + c0];
            #pragma unroll
            for (int pi = 0; pi < 4; pi++){
                float4 xv = *(const float4*)&yg_t[pr + pi][dd];
                acc[pi][0] = fmaf(xv.x, w0.x, fmaf(xv.y, w1.x, fmaf(xv.z, w2.x, fmaf(xv.w, w3.x, acc[pi][0]))));
                acc[pi][1] = fmaf(xv.x, w0.y, fmaf(xv.y, w1.y, fmaf(xv.z, w2.y, fmaf(xv.w, w3.y, acc[pi][1]))));
                acc[pi][2] = fmaf(xv.x, w0.z, fmaf(xv.y, w1.z, fmaf(xv.z, w2.z, fmaf(xv.w, w3.z, acc[pi][2]))));
                acc[pi][3] = fmaf(xv.x, w0.w, fmaf(xv.y, w1.w, fmaf(xv.z, w2.w, fmaf(xv.w, w3.w, acc[pi][3]))));
            }
        }
        float4 bv = *(const float4*)&Wob[c0];
        #pragma unroll
        for (int pi = 0; pi < 4; pi++){
            float4 ov = make_float4(acc[pi][0] + bv.x, acc[pi][1] + bv.y,
                                    acc[pi][2] + bv.z, acc[pi][3] + bv.w);
            *(float4*)&out[(size_t)(p0 + pr + pi) * 192 + c0] = ov;
        }
    }
}

extern "C" void kernel_launch(void* const* d_in, const int* in_sizes, int n_in,
                              void* d_out, int out_size, void* d_ws, size_t ws_size,
                              hipStream_t stream) {
    const float* x    = (const float*)d_in[0];
    const float* Win  = (const float*)d_in[1];
    const float* Winb = (const float*)d_in[2];
    const float* xpw  = (const float*)d_in[3];
    const float* dtTw = (const float*)d_in[4];
    const float* dtTb = (const float*)d_in[5];
    const float* dtLw = (const float*)d_in[6];
    const float* dtLb = (const float*)d_in[7];
    const float* ATl  = (const float*)d_in[8];
    const float* ALl  = (const float*)d_in[9];
    const float* Dsk  = (const float*)d_in[10];
    const float* Wo   = (const float*)d_in[11];
    const float* Wob  = (const float*)d_in[12];
    float* out = (float*)d_out;
    float* ws  = (float*)d_ws;

    hipLaunchKernelGGL(prep_k,     dim3(613),  dim3(256), 0, stream, Win, xpw, dtTw, dtLw, Wo, ATl, ALl, ws);
    hipLaunchKernelGGL(proj_k,     dim3(512),  dim3(256), 0, stream, x, Winb, dtTb, dtLb, ws);
    hipLaunchKernelGGL(repack_k,   dim3(1152), dim3(256), 0, stream, ws);
    hipLaunchKernelGGL(repackbc_k, dim3(24),   dim3(256), 0, stream, ws);
    hipLaunchKernelGGL(scan_k,     dim3(768),  dim3(128), 0, stream, ATl, ALl, ws);
    hipLaunchKernelGGL(ysum_k,     dim3(384),  dim3(256), 0, stream, Dsk, ws);
    hipLaunchKernelGGL(out_k,      dim3(512),  dim3(256), 0, stream, Wob, ws, out);
}

// Round 4
// 160.818 us; speedup vs baseline: 1.5712x; 1.1669x over previous
//
#include <hip/hip_runtime.h>
#include <math.h>

#define DM 192
#define RNK 12
#define NS 16
#define NO2 432

// workspace float offsets
#define OFF_FLAG   156672u
#define OFF_U      156688u            // row-major planes [bd][4096]; partial-y(0) after repack
#define OFF_DT     1729552u           // = OFF_U + 384*4096 ; YG after scan
#define OFF_DL     3302416u           // = OFF_U + 768*4096 ; partial-y(1) after repack
#define OFF_BC3    4875280u           // float4-interleaved [b*12+grp][4096][4]
#define OFF_DIAG   5268496u           // 1152 scalar diag planes + 24 float4 diag planes
#define OFF_BC4D   (OFF_DIAG + 1152u*4096u)
// bf16 weight region (shorts, at ws base): hi/lo split weights
#define SW_WINH 0u
#define SW_WINL 36864u
#define SW_WCH  73728u
#define SW_WCL  156672u
#define SW_WOH  239616u
#define SW_WOL  276480u
// (313344 shorts = 156672 floats, exactly the region before OFF_FLAG)

typedef __attribute__((ext_vector_type(8))) short short8v;
typedef __attribute__((ext_vector_type(4))) float floatx4;

__device__ __forceinline__ float gelu_f(float x){
    return 0.5f * x * (1.0f + erff(x * 0.70710678118654752f));
}
__device__ __forceinline__ float softplus_f(float x){
    return fmaxf(x, 0.0f) + log1pf(__expf(-fabsf(x)));
}
__device__ __forceinline__ int diag_off(int s){
    return (s <= 64) ? ((s * (s + 1)) >> 1) : (2080 + (((s - 64) * (191 - s)) >> 1));
}
__device__ __forceinline__ unsigned short bf16_rte(float f){
    unsigned u = __float_as_uint(f);
    unsigned r = (u + 0x7fffu + ((u >> 16) & 1u)) >> 16;
    return (unsigned short)r;
}
__device__ __forceinline__ float bf16_f(unsigned short h){
    return __uint_as_float(((unsigned)h) << 16);
}
// split 8 consecutive floats (two float4) into bf16 hi/lo fragments
__device__ __forceinline__ void split8(float4 v0, float4 v1, short8v& hi, short8v& lo){
    float f[8] = {v0.x, v0.y, v0.z, v0.w, v1.x, v1.y, v1.z, v1.w};
    #pragma unroll
    for (int e = 0; e < 8; e++){
        unsigned short h = bf16_rte(f[e]);
        hi[e] = (short)h;
        lo[e] = (short)bf16_rte(f[e] - bf16_f(h));
    }
}

// ---------------- prep: bf16 hi/lo weight splits + A-structure flag ----------------
__global__ __launch_bounds__(256) void prep_k(const float* __restrict__ Win,
                                              const float* __restrict__ xpw,
                                              const float* __restrict__ dtwT,
                                              const float* __restrict__ dtwL,
                                              const float* __restrict__ Wout,
                                              const float* __restrict__ ATl,
                                              const float* __restrict__ ALl,
                                              float* __restrict__ ws){
    unsigned short* __restrict__ wsu = (unsigned short*)ws;
    if (blockIdx.x == 612){
        __shared__ int okf;
        if (threadIdx.x == 0) okf = 1;
        __syncthreads();
        bool ok = true;
        for (int t = threadIdx.x; t < 6144; t += 256){
            const float* arr = (t < 3072) ? ATl : ALl;
            int e = (t < 3072) ? t : t - 3072;
            int n = e & 15;
            ok = ok && (fabsf(arr[e] - logf((float)(n + 1))) < 1e-5f);
        }
        if (!ok) atomicAnd(&okf, 0);
        __syncthreads();
        if (threadIdx.x == 0) ws[OFF_FLAG] = okf ? 1.0f : 0.0f;
        return;
    }
    int idx = blockIdx.x * 256 + threadIdx.x;
    float w;
    unsigned hioff, looff, rel;
    if (idx < 36864){                 // Win [d_out][c] -> [n][k] as-is
        w = Win[idx]; hioff = SW_WINH; looff = SW_WINL; rel = idx;
    } else if (idx < 119808){         // Wcomb [o][c]
        int t = idx - 36864;
        int o = t / DM, c = t - o * DM;
        float acc = 0.f;
        if (o < 192){
            #pragma unroll
            for (int r = 0; r < RNK; r++) acc += dtwT[o * RNK + r] * xpw[r * DM + c];
        } else if (o < 384){
            int d2 = o - 192;
            #pragma unroll
            for (int r = 0; r < RNK; r++) acc += dtwL[d2 * RNK + r] * xpw[(RNK + r) * DM + c];
        } else {
            acc = xpw[(2 * RNK + (o - 384)) * DM + c];
        }
        w = acc; hioff = SW_WCH; looff = SW_WCL; rel = t;
    } else if (idx < 156672){         // Wout [c][d] -> [n][k] as-is
        int t = idx - 119808;
        w = Wout[t]; hioff = SW_WOH; looff = SW_WOL; rel = t;
    } else return;
    unsigned short h = bf16_rte(w);
    wsu[hioff + rel] = h;
    wsu[looff + rel] = bf16_rte(w - bf16_f(h));
}

// ---------------- fused projections via bf16x3 MFMA ----------------
// 256 blocks x 256 thr (4 waves). Block covers 32 positions.
// wave (pg, nh): pg = pos-half (16 pos), nh = N-half.
__global__ __launch_bounds__(256) void proj_k(const float* __restrict__ x,
                                              const float* __restrict__ inb,
                                              const float* __restrict__ dtTb,
                                              const float* __restrict__ dtLb,
                                              float* __restrict__ ws){
    __shared__ float u_t[32][196];
    const unsigned short* __restrict__ wsu = (const unsigned short*)ws;
    const int P0 = blockIdx.x * 32;
    const int b = P0 >> 12;
    const int prel = P0 & 4095;
    const int tid = threadIdx.x;
    const int wv = tid >> 6, lane = tid & 63;
    const int pg = wv >> 1, nh = wv & 1;
    const int lr = lane & 15, lg = lane >> 4;
    const int prow = pg * 16 + lr;            // A-frag row (position)

    // ---- G1: u = gelu(x @ Win^T + b) ----
    short8v xh[6], xl[6];
    #pragma unroll
    for (int ks = 0; ks < 6; ks++){
        const float* xp = x + (size_t)(P0 + prow) * 192 + ks * 32 + lg * 8;
        split8(*(const float4*)xp, *(const float4*)(xp + 4), xh[ks], xl[ks]);
    }
    float* __restrict__ u_ws = ws + OFF_U;
    #pragma unroll
    for (int tp = 0; tp < 3; tp++){           // 6 tiles as 3 pairs
        const int n0a = (nh * 6 + tp * 2) * 16;
        const int n0b = n0a + 16;
        floatx4 acA = {0.f, 0.f, 0.f, 0.f}, acB = {0.f, 0.f, 0.f, 0.f};
        #pragma unroll
        for (int ks = 0; ks < 6; ks++){
            const short8v bhA = *(const short8v*)(wsu + SW_WINH + (size_t)(n0a + lr) * 192 + ks * 32 + lg * 8);
            const short8v blA = *(const short8v*)(wsu + SW_WINL + (size_t)(n0a + lr) * 192 + ks * 32 + lg * 8);
            const short8v bhB = *(const short8v*)(wsu + SW_WINH + (size_t)(n0b + lr) * 192 + ks * 32 + lg * 8);
            const short8v blB = *(const short8v*)(wsu + SW_WINL + (size_t)(n0b + lr) * 192 + ks * 32 + lg * 8);
            acA = __builtin_amdgcn_mfma_f32_16x16x32_bf16(xh[ks], bhA, acA, 0, 0, 0);
            acB = __builtin_amdgcn_mfma_f32_16x16x32_bf16(xh[ks], bhB, acB, 0, 0, 0);
            acA = __builtin_amdgcn_mfma_f32_16x16x32_bf16(xh[ks], blA, acA, 0, 0, 0);
            acB = __builtin_amdgcn_mfma_f32_16x16x32_bf16(xh[ks], blB, acB, 0, 0, 0);
            acA = __builtin_amdgcn_mfma_f32_16x16x32_bf16(xl[ks], bhA, acA, 0, 0, 0);
            acB = __builtin_amdgcn_mfma_f32_16x16x32_bf16(xl[ks], bhB, acB, 0, 0, 0);
        }
        const float biasA = inb[n0a + lr], biasB = inb[n0b + lr];
        #pragma unroll
        for (int r = 0; r < 4; r++){
            const int pl = pg * 16 + lg * 4 + r;
            const float va = gelu_f(acA[r] + biasA);
            const float vb = gelu_f(acB[r] + biasB);
            u_t[pl][n0a + lr] = va;
            u_t[pl][n0b + lr] = vb;
            u_ws[(size_t)(b * 192 + n0a + lr) * 4096 + prel + pl] = va;
            u_ws[(size_t)(b * 192 + n0b + lr) * 4096 + prel + pl] = vb;
        }
    }
    __syncthreads();

    // ---- G2: [dT | dL | BC] = u @ Wcomb^T ----
    short8v uh[6], ul[6];
    #pragma unroll
    for (int ks = 0; ks < 6; ks++){
        const float* up = &u_t[prow][ks * 32 + lg * 8];
        split8(*(const float4*)up, *(const float4*)(up + 4), uh[ks], ul[ks]);
    }
    float* __restrict__ dT_ws = ws + OFF_DT;
    float* __restrict__ dL_ws = ws + OFF_DL;
    // nh==0: tiles 0..13 ; nh==1: tiles 14..26
    const int t0 = nh ? 14 : 0;
    const int nt_cnt = nh ? 13 : 14;
    for (int tp = 0; tp < nt_cnt; tp += 2){
        const bool dual = (tp + 1 < nt_cnt);
        const int ntA = t0 + tp, ntB = dual ? (t0 + tp + 1) : ntA;
        const int n0a = ntA * 16, n0b = ntB * 16;
        floatx4 acA = {0.f, 0.f, 0.f, 0.f}, acB = {0.f, 0.f, 0.f, 0.f};
        #pragma unroll
        for (int ks = 0; ks < 6; ks++){
            const short8v bhA = *(const short8v*)(wsu + SW_WCH + (size_t)(n0a + lr) * 192 + ks * 32 + lg * 8);
            const short8v blA = *(const short8v*)(wsu + SW_WCL + (size_t)(n0a + lr) * 192 + ks * 32 + lg * 8);
            acA = __builtin_amdgcn_mfma_f32_16x16x32_bf16(uh[ks], bhA, acA, 0, 0, 0);
            acA = __builtin_amdgcn_mfma_f32_16x16x32_bf16(uh[ks], blA, acA, 0, 0, 0);
            acA = __builtin_amdgcn_mfma_f32_16x16x32_bf16(ul[ks], bhA, acA, 0, 0, 0);
            if (dual){
                const short8v bhB = *(const short8v*)(wsu + SW_WCH + (size_t)(n0b + lr) * 192 + ks * 32 + lg * 8);
                const short8v blB = *(const short8v*)(wsu + SW_WCL + (size_t)(n0b + lr) * 192 + ks * 32 + lg * 8);
                acB = __builtin_amdgcn_mfma_f32_16x16x32_bf16(uh[ks], bhB, acB, 0, 0, 0);
                acB = __builtin_amdgcn_mfma_f32_16x16x32_bf16(uh[ks], blB, acB, 0, 0, 0);
                acB = __builtin_amdgcn_mfma_f32_16x16x32_bf16(ul[ks], bhB, acB, 0, 0, 0);
            }
        }
        #pragma unroll
        for (int half = 0; half < 2; half++){
            if (half == 1 && !dual) break;
            const floatx4 ac = half ? acB : acA;
            const int o = (half ? n0b : n0a) + lr;
            if (o < 192){
                const float bb = dtTb[o];
                #pragma unroll
                for (int r = 0; r < 4; r++)
                    dT_ws[(size_t)(b * 192 + o) * 4096 + prel + pg * 16 + lg * 4 + r] = softplus_f(ac[r] + bb);
            } else if (o < 384){
                const float bb = dtLb[o - 192];
                #pragma unroll
                for (int r = 0; r < 4; r++)
                    dL_ws[(size_t)(b * 192 + o - 192) * 4096 + prel + pg * 16 + lg * 4 + r] = softplus_f(ac[r] + bb);
            } else {
                const int c4 = (o - 384) >> 4;     // 0=BT 1=BL 2=C
                const int ng = lr >> 2, comp = lr & 3;
                const size_t pb = (size_t)(b * 12 + c4 * 4 + ng) * 4096;
                #pragma unroll
                for (int r = 0; r < 4; r++)
                    ws[OFF_BC3 + (pb + prel + pg * 16 + lg * 4 + r) * 4 + comp] = ac[r];
            }
        }
    }
}

// ---------------- repack scalar planes (u,dT,dL) row-major -> packed diag ----------------
__global__ __launch_bounds__(256) void repack_k(float* __restrict__ ws){
    __shared__ float ldsf[4096];
    const int p = blockIdx.x;                   // 0..1151
    const float4* __restrict__ src4 = (const float4*)(ws + OFF_U + (size_t)p * 4096);
    float* __restrict__ dst = ws + OFF_DIAG + (size_t)p * 4096;
    const int tid = threadIdx.x;
    float4* lds4 = (float4*)ldsf;
    #pragma unroll
    for (int k = 0; k < 4; k++) lds4[tid + k * 256] = src4[tid + k * 256];
    __syncthreads();
    const int wv = tid >> 6, j2 = tid & 63;
    for (int s = wv; s < 127; s += 4){
        const int jmin = (s > 63) ? (s - 63) : 0;
        const int jmax = (s < 63) ? s : 63;
        const int len = jmax - jmin + 1;
        if (j2 < len){
            const int j = jmin + j2;
            dst[diag_off(s) + j2] = ldsf[(s - j) * 64 + j];
        }
    }
}

// ---------------- repack BC float4 planes row-major -> packed diag ----------------
__global__ __launch_bounds__(256) void repackbc_k(float* __restrict__ ws){
    __shared__ float4 l4[4096];                 // 64 KB
    const int p = blockIdx.x;                   // 0..23
    const float4* __restrict__ src = (const float4*)(ws + OFF_BC3) + (size_t)p * 4096;
    float4* __restrict__ dst = (float4*)(ws + OFF_BC4D) + (size_t)p * 4096;
    const int tid = threadIdx.x;
    #pragma unroll
    for (int k = 0; k < 16; k++) l4[tid + k * 256] = src[tid + k * 256];
    __syncthreads();
    const int wv = tid >> 6, j2 = tid & 63;
    for (int s = wv; s < 127; s += 4){
        const int jmin = (s > 63) ? (s - 63) : 0;
        const int jmax = (s < 63) ? s : 63;
        const int len = jmax - jmin + 1;
        if (j2 < len){
            const int j = jmin + j2;
            dst[diag_off(s) + j2] = l4[(s - j) * 64 + j];
        }
    }
}

// ---------------- diagonal wavefront scan (unchanged from round 3) ----------------
#define LOADSET(pfx, sv) do {                                                   \
    const int sv_ = (sv);                                                       \
    const int sc_ = sv_ < 126 ? sv_ : 126;                                      \
    const int jmin_ = (sc_ > 63) ? (sc_ - 63) : 0;                              \
    pfx##_q = diag_off(sc_) - jmin_ + j;                                        \
    pfx##_dT = pdT[pfx##_q]; pfx##_dL = pdL[pfx##_q]; pfx##_u = pu[pfx##_q];    \
    pfx##_bt = pBT[pfx##_q]; pfx##_bl = pBL[pfx##_q]; pfx##_cc = pC[pfx##_q];   \
} while (0)

#define STEP(pfx, sv) do {                                                      \
    const float dT_ = pfx##_dT, dL_ = pfx##_dL, u_ = pfx##_u;                   \
    const float bt_[4] = {pfx##_bt.x, pfx##_bt.y, pfx##_bt.z, pfx##_bt.w};      \
    const float bl_[4] = {pfx##_bl.x, pfx##_bl.y, pfx##_bl.z, pfx##_bl.w};      \
    const float cc_[4] = {pfx##_cc.x, pfx##_cc.y, pfx##_cc.z, pfx##_cc.w};      \
    const int q_ = pfx##_q;                                                     \
    LOADSET(pfx, (sv) + 3);                                                     \
    float da_[4], dl_[4];                                                       \
    if (sflag){                                                                 \
        const float E_ = __expf(-dT_), F_ = __expf(-dL_);                       \
        da_[0] = __expf(nA1 * dT_); dl_[0] = __expf(nA1 * dL_);                 \
        da_[1] = da_[0] * E_; da_[2] = da_[1] * E_; da_[3] = da_[2] * E_;       \
        dl_[1] = dl_[0] * F_; dl_[2] = dl_[1] * F_; dl_[3] = dl_[2] * F_;       \
    } else {                                                                    \
        da_[0] = __expf(dT_ * ATr[0]); da_[1] = __expf(dT_ * ATr[1]);           \
        da_[2] = __expf(dT_ * ATr[2]); da_[3] = __expf(dT_ * ATr[3]);           \
        dl_[0] = __expf(dL_ * ALr[0]); dl_[1] = __expf(dL_ * ALr[1]);           \
        dl_[2] = __expf(dL_ * ALr[2]); dl_[3] = __expf(dL_ * ALr[3]);           \
    }                                                                           \
    const int ic_ = (sv) - j;                                                   \
    const bool act_ = ((unsigned)ic_) < 64u;                                    \
    const float udT_ = u_ * dT_, udL_ = u_ * dL_;                               \
    float y_ = 0.f;                                                             \
    _Pragma("unroll")                                                           \
    for (int k = 0; k < 4; k++){                                                \
        float hl_ = __shfl_up(h[k], 1u, 64);                                    \
        hl_ = (j == 0) ? 0.f : hl_;                                             \
        float hn_ = fmaf(da_[k], h[k], fmaf(dl_[k], hl_, fmaf(udT_, bt_[k], udL_ * bl_[k]))); \
        h[k] = act_ ? hn_ : h[k];                                               \
        y_ = fmaf(hn_, cc_[k], y_);                                             \
    }                                                                           \
    if (act_) ylds[wv][q_] = y_;                                                \
} while (0)

__global__ __launch_bounds__(128) void scan_k(const float* __restrict__ ATl,
                                              const float* __restrict__ ALl,
                                              float* __restrict__ ws){
    __shared__ float ylds[2][4096];             // 32 KB
    const int bx = blockIdx.x;
    const int bd = bx >> 1, half = bx & 1;
    const int b = bd / 192, d = bd - b * 192;
    const int tid = threadIdx.x;
    const int wv = tid >> 6, j = tid & 63;
    const int n0 = half * 8 + wv * 4;
    const int ng = half * 2 + wv;

    const float* __restrict__ pu  = ws + OFF_DIAG + (size_t)bd * 4096;
    const float* __restrict__ pdT = ws + OFF_DIAG + (size_t)(384 + bd) * 4096;
    const float* __restrict__ pdL = ws + OFF_DIAG + (size_t)(768 + bd) * 4096;
    const float4* __restrict__ bc4 = (const float4*)(ws + OFF_BC4D) + (size_t)(b * 12) * 4096;
    const float4* __restrict__ pBT = bc4 + (size_t)(0 + ng) * 4096;
    const float4* __restrict__ pBL = bc4 + (size_t)(4 + ng) * 4096;
    const float4* __restrict__ pC  = bc4 + (size_t)(8 + ng) * 4096;
    float* __restrict__ pY = ws + (half ? OFF_DL : OFF_U) + (size_t)bd * 4096;

    const bool sflag = (ws[OFF_FLAG] > 0.5f);
    const float nA1 = -(float)(n0 + 1);
    float ATr[4], ALr[4];
    if (!sflag){
        #pragma unroll
        for (int k = 0; k < 4; k++){
            ATr[k] = -expf(ATl[d * NS + n0 + k]);
            ALr[k] = -expf(ALl[d * NS + n0 + k]);
        }
    } else {
        #pragma unroll
        for (int k = 0; k < 4; k++){ ATr[k] = 0.f; ALr[k] = 0.f; }
    }
    float h[4] = {0.f, 0.f, 0.f, 0.f};

    int a_q, b_q, c_q;
    float a_dT, a_dL, a_u; float4 a_bt, a_bl, a_cc;
    float b_dT, b_dL, b_u; float4 b_bt, b_bl, b_cc;
    float c_dT, c_dL, c_u; float4 c_bt, c_bl, c_cc;
    LOADSET(a, 0);
    LOADSET(b, 1);
    LOADSET(c, 2);

    for (int s = 0; s < 129; s += 3){
        STEP(a, s);
        STEP(b, s + 1);
        STEP(c, s + 2);
    }

    __syncthreads();
    for (int idx = tid; idx < 4096; idx += 128)
        pY[idx] = ylds[0][idx] + ylds[1][idx];
}

// ---------------- y-sum + gelu (output stays diag-indexed per-bd planes in OFF_DT) -------
__global__ __launch_bounds__(256) void ysum_k(const float* __restrict__ Dskp,
                                              float* __restrict__ ws){
    __shared__ float yl[4096];
    const int bd = blockIdx.x;
    const int d = bd % 192;
    const int tid = threadIdx.x;
    const float* __restrict__ p0 = ws + OFF_U  + (size_t)bd * 4096;
    const float* __restrict__ p1 = ws + OFF_DL + (size_t)bd * 4096;
    const float* __restrict__ pu = ws + OFF_DIAG + (size_t)bd * 4096;
    float* __restrict__ yg = ws + OFF_DT + (size_t)bd * 4096;
    const float Dsk = Dskp[d];
    #pragma unroll
    for (int k = 0; k < 16; k++){
        const int idx = tid + k * 256;
        yl[idx] = gelu_f(p0[idx] + p1[idx] + pu[idx] * Dsk);
    }
    __syncthreads();
    #pragma unroll
    for (int k = 0; k < 16; k++){
        const int idx = tid + k * 256;
        const int i = idx >> 6, jj = idx & 63;
        const int s = i + jj;
        const int jmin = (s > 63) ? (s - 63) : 0;
        yg[idx] = yl[diag_off(s) + jj - jmin];
    }
}

// ---------------- out projection via bf16x3 MFMA ----------------
// 256 blocks x 256 thr (4 waves), 32 positions per block.
__global__ __launch_bounds__(256) void out_k(const float* __restrict__ Wob,
                                             float* __restrict__ ws,
                                             float* __restrict__ out){
    __shared__ float yg_t[32][196];
    const unsigned short* __restrict__ wsu = (const unsigned short*)ws;
    const int P0 = blockIdx.x * 32;
    const int b = P0 >> 12;
    const int prel = P0 & 4095;
    const int tid = threadIdx.x;

    // stage yg [d][pos] -> LDS [pos][d]
    for (int idx = tid; idx < 384; idx += 256){
        const int d = idx >> 1, h16 = idx & 1;
        const float* src = ws + OFF_DT + (size_t)(b * 192 + d) * 4096 + prel + h16 * 16;
        #pragma unroll
        for (int q = 0; q < 4; q++){
            float4 v = *(const float4*)&src[q * 4];
            yg_t[h16 * 16 + q * 4 + 0][d] = v.x;
            yg_t[h16 * 16 + q * 4 + 1][d] = v.y;
            yg_t[h16 * 16 + q * 4 + 2][d] = v.z;
            yg_t[h16 * 16 + q * 4 + 3][d] = v.w;
        }
    }
    __syncthreads();

    const int wv = tid >> 6, lane = tid & 63;
    const int pg = wv >> 1, nh = wv & 1;
    const int lr = lane & 15, lg = lane >> 4;
    const int prow = pg * 16 + lr;

    short8v yh[6], yl2[6];
    #pragma unroll
    for (int ks = 0; ks < 6; ks++){
        const float* yp = &yg_t[prow][ks * 32 + lg * 8];
        split8(*(const float4*)yp, *(const float4*)(yp + 4), yh[ks], yl2[ks]);
    }
    #pragma unroll
    for (int tp = 0; tp < 3; tp++){
        const int n0a = (nh * 6 + tp * 2) * 16;
        const int n0b = n0a + 16;
        floatx4 acA = {0.f, 0.f, 0.f, 0.f}, acB = {0.f, 0.f, 0.f, 0.f};
        #pragma unroll
        for (int ks = 0; ks < 6; ks++){
            const short8v bhA = *(const short8v*)(wsu + SW_WOH + (size_t)(n0a + lr) * 192 + ks * 32 + lg * 8);
            const short8v blA = *(const short8v*)(wsu + SW_WOL + (size_t)(n0a + lr) * 192 + ks * 32 + lg * 8);
            const short8v bhB = *(const short8v*)(wsu + SW_WOH + (size_t)(n0b + lr) * 192 + ks * 32 + lg * 8);
            const short8v blB = *(const short8v*)(wsu + SW_WOL + (size_t)(n0b + lr) * 192 + ks * 32 + lg * 8);
            acA = __builtin_amdgcn_mfma_f32_16x16x32_bf16(yh[ks], bhA, acA, 0, 0, 0);
            acB = __builtin_amdgcn_mfma_f32_16x16x32_bf16(yh[ks], bhB, acB, 0, 0, 0);
            acA = __builtin_amdgcn_mfma_f32_16x16x32_bf16(yh[ks], blA, acA, 0, 0, 0);
            acB = __builtin_amdgcn_mfma_f32_16x16x32_bf16(yh[ks], blB, acB, 0, 0, 0);
            acA = __builtin_amdgcn_mfma_f32_16x16x32_bf16(yl2[ks], bhA, acA, 0, 0, 0);
            acB = __builtin_amdgcn_mfma_f32_16x16x32_bf16(yl2[ks], bhB, acB, 0, 0, 0);
        }
        const float biasA = Wob[n0a + lr], biasB = Wob[n0b + lr];
        #pragma unroll
        for (int r = 0; r < 4; r++){
            const int pos = P0 + pg * 16 + lg * 4 + r;
            out[(size_t)pos * 192 + n0a + lr] = acA[r] + biasA;
            out[(size_t)pos * 192 + n0b + lr] = acB[r] + biasB;
        }
    }
}

extern "C" void kernel_launch(void* const* d_in, const int* in_sizes, int n_in,
                              void* d_out, int out_size, void* d_ws, size_t ws_size,
                              hipStream_t stream) {
    const float* x    = (const float*)d_in[0];
    const float* Win  = (const float*)d_in[1];
    const float* Winb = (const float*)d_in[2];
    const float* xpw  = (const float*)d_in[3];
    const float* dtTw = (const float*)d_in[4];
    const float* dtTb = (const float*)d_in[5];
    const float* dtLw = (const float*)d_in[6];
    const float* dtLb = (const float*)d_in[7];
    const float* ATl  = (const float*)d_in[8];
    const float* ALl  = (const float*)d_in[9];
    const float* Dsk  = (const float*)d_in[10];
    const float* Wo   = (const float*)d_in[11];
    const float* Wob  = (const float*)d_in[12];
    float* out = (float*)d_out;
    float* ws  = (float*)d_ws;

    hipLaunchKernelGGL(prep_k,     dim3(613),  dim3(256), 0, stream, Win, xpw, dtTw, dtLw, Wo, ATl, ALl, ws);
    hipLaunchKernelGGL(proj_k,     dim3(256),  dim3(256), 0, stream, x, Winb, dtTb, dtLb, ws);
    hipLaunchKernelGGL(repack_k,   dim3(1152), dim3(256), 0, stream, ws);
    hipLaunchKernelGGL(repackbc_k, dim3(24),   dim3(256), 0, stream, ws);
    hipLaunchKernelGGL(scan_k,     dim3(768),  dim3(128), 0, stream, ATl, ALl, ws);
    hipLaunchKernelGGL(ysum_k,     dim3(384),  dim3(256), 0, stream, Dsk, ws);
    hipLaunchKernelGGL(out_k,      dim3(256),  dim3(256), 0, stream, Wob, ws, out);
}

// Round 5
// 140.702 us; speedup vs baseline: 1.7958x; 1.1430x over previous
//
#include <hip/hip_runtime.h>
#include <math.h>

#define DM 192
#define RNK 12
#define NS 16
#define NO2 432

// workspace float offsets
#define OFF_FLAG   156672u
#define OFF_U      156688u            // row-major planes [bd][4096]; partial-y(0) after repack
#define OFF_DT     1729552u           // = OFF_U + 384*4096 ; YG after scan
#define OFF_DL     3302416u           // = OFF_U + 768*4096 ; partial-y(1) after repack
#define OFF_BC3    4875280u           // float4-interleaved [b*12+grp][4096][4]
#define OFF_DIAG   5268496u           // 1152 scalar diag planes + 24 float4 diag planes
#define OFF_BC4D   (OFF_DIAG + 1152u*4096u)
// bf16 weight region (shorts, at ws base): hi/lo split weights
#define SW_WINH 0u
#define SW_WINL 36864u
#define SW_WCH  73728u
#define SW_WCL  156672u
#define SW_WOH  239616u
#define SW_WOL  276480u

typedef __attribute__((ext_vector_type(8))) short short8v;
typedef __attribute__((ext_vector_type(4))) float floatx4;

__device__ __forceinline__ float gelu_f(float x){
    return 0.5f * x * (1.0f + erff(x * 0.70710678118654752f));
}
__device__ __forceinline__ float softplus_f(float x){
    return fmaxf(x, 0.0f) + log1pf(__expf(-fabsf(x)));
}
__device__ __forceinline__ int diag_off(int s){
    return (s <= 64) ? ((s * (s + 1)) >> 1) : (2080 + (((s - 64) * (191 - s)) >> 1));
}
__device__ __forceinline__ unsigned short bf16_rte(float f){
    unsigned u = __float_as_uint(f);
    unsigned r = (u + 0x7fffu + ((u >> 16) & 1u)) >> 16;
    return (unsigned short)r;
}
__device__ __forceinline__ float bf16_f(unsigned short h){
    return __uint_as_float(((unsigned)h) << 16);
}
__device__ __forceinline__ void split8(float4 v0, float4 v1, short8v& hi, short8v& lo){
    float f[8] = {v0.x, v0.y, v0.z, v0.w, v1.x, v1.y, v1.z, v1.w};
    #pragma unroll
    for (int e = 0; e < 8; e++){
        unsigned short h = bf16_rte(f[e]);
        hi[e] = (short)h;
        lo[e] = (short)bf16_rte(f[e] - bf16_f(h));
    }
}

// ---------------- prep: bf16 hi/lo weight splits + A-structure flag ----------------
__global__ __launch_bounds__(256) void prep_k(const float* __restrict__ Win,
                                              const float* __restrict__ xpw,
                                              const float* __restrict__ dtwT,
                                              const float* __restrict__ dtwL,
                                              const float* __restrict__ Wout,
                                              const float* __restrict__ ATl,
                                              const float* __restrict__ ALl,
                                              float* __restrict__ ws){
    unsigned short* __restrict__ wsu = (unsigned short*)ws;
    if (blockIdx.x == 612){
        __shared__ int okf;
        if (threadIdx.x == 0) okf = 1;
        __syncthreads();
        bool ok = true;
        for (int t = threadIdx.x; t < 6144; t += 256){
            const float* arr = (t < 3072) ? ATl : ALl;
            int e = (t < 3072) ? t : t - 3072;
            int n = e & 15;
            ok = ok && (fabsf(arr[e] - logf((float)(n + 1))) < 1e-5f);
        }
        if (!ok) atomicAnd(&okf, 0);
        __syncthreads();
        if (threadIdx.x == 0) ws[OFF_FLAG] = okf ? 1.0f : 0.0f;
        return;
    }
    int idx = blockIdx.x * 256 + threadIdx.x;
    float w;
    unsigned hioff, looff, rel;
    if (idx < 36864){
        w = Win[idx]; hioff = SW_WINH; looff = SW_WINL; rel = idx;
    } else if (idx < 119808){
        int t = idx - 36864;
        int o = t / DM, c = t - o * DM;
        float acc = 0.f;
        if (o < 192){
            #pragma unroll
            for (int r = 0; r < RNK; r++) acc += dtwT[o * RNK + r] * xpw[r * DM + c];
        } else if (o < 384){
            int d2 = o - 192;
            #pragma unroll
            for (int r = 0; r < RNK; r++) acc += dtwL[d2 * RNK + r] * xpw[(RNK + r) * DM + c];
        } else {
            acc = xpw[(2 * RNK + (o - 384)) * DM + c];
        }
        w = acc; hioff = SW_WCH; looff = SW_WCL; rel = t;
    } else if (idx < 156672){
        int t = idx - 119808;
        w = Wout[t]; hioff = SW_WOH; looff = SW_WOL; rel = t;
    } else return;
    unsigned short h = bf16_rte(w);
    wsu[hioff + rel] = h;
    wsu[looff + rel] = bf16_rte(w - bf16_f(h));
}

// ---------------- fused projections via bf16x3 MFMA, LDS-staged coalesced stores ---------
// 512 blocks x 256 thr (4 waves). Block covers 16 positions; wave wv owns an N-slice.
__global__ __launch_bounds__(256) void proj_k(const float* __restrict__ x,
                                              const float* __restrict__ inb,
                                              const float* __restrict__ dtTb,
                                              const float* __restrict__ dtLb,
                                              float* __restrict__ ws){
    __shared__ float u_t[16][196];
    __shared__ float g2[16][436];
    const unsigned short* __restrict__ wsu = (const unsigned short*)ws;
    const int P0 = blockIdx.x * 16;
    const int b = P0 >> 12;
    const int prel = P0 & 4095;
    const int tid = threadIdx.x;
    const int wv = tid >> 6, lane = tid & 63;
    const int lr = lane & 15, lg = lane >> 4;

    // ---- G1: u = gelu(x @ Win^T + b) ; wave wv -> n-tiles wv*3..wv*3+2 ----
    short8v xh[6], xl[6];
    #pragma unroll
    for (int ks = 0; ks < 6; ks++){
        const float* xp = x + (size_t)(P0 + lr) * 192 + ks * 32 + lg * 8;
        split8(*(const float4*)xp, *(const float4*)(xp + 4), xh[ks], xl[ks]);
    }
    {
        floatx4 ac0 = {0.f,0.f,0.f,0.f}, ac1 = {0.f,0.f,0.f,0.f}, ac2 = {0.f,0.f,0.f,0.f};
        const int n0 = wv * 48;
        #pragma unroll
        for (int ks = 0; ks < 6; ks++){
            const size_t rb = (size_t)(n0 + lr) * 192 + ks * 32 + lg * 8;
            const short8v bh0 = *(const short8v*)(wsu + SW_WINH + rb);
            const short8v bl0 = *(const short8v*)(wsu + SW_WINL + rb);
            const short8v bh1 = *(const short8v*)(wsu + SW_WINH + rb + 16*192);
            const short8v bl1 = *(const short8v*)(wsu + SW_WINL + rb + 16*192);
            const short8v bh2 = *(const short8v*)(wsu + SW_WINH + rb + 32*192);
            const short8v bl2 = *(const short8v*)(wsu + SW_WINL + rb + 32*192);
            ac0 = __builtin_amdgcn_mfma_f32_16x16x32_bf16(xh[ks], bh0, ac0, 0, 0, 0);
            ac1 = __builtin_amdgcn_mfma_f32_16x16x32_bf16(xh[ks], bh1, ac1, 0, 0, 0);
            ac2 = __builtin_amdgcn_mfma_f32_16x16x32_bf16(xh[ks], bh2, ac2, 0, 0, 0);
            ac0 = __builtin_amdgcn_mfma_f32_16x16x32_bf16(xh[ks], bl0, ac0, 0, 0, 0);
            ac1 = __builtin_amdgcn_mfma_f32_16x16x32_bf16(xh[ks], bl1, ac1, 0, 0, 0);
            ac2 = __builtin_amdgcn_mfma_f32_16x16x32_bf16(xh[ks], bl2, ac2, 0, 0, 0);
            ac0 = __builtin_amdgcn_mfma_f32_16x16x32_bf16(xl[ks], bh0, ac0, 0, 0, 0);
            ac1 = __builtin_amdgcn_mfma_f32_16x16x32_bf16(xl[ks], bh1, ac1, 0, 0, 0);
            ac2 = __builtin_amdgcn_mfma_f32_16x16x32_bf16(xl[ks], bh2, ac2, 0, 0, 0);
        }
        const float b0 = inb[n0 + lr], b1 = inb[n0 + 16 + lr], b2 = inb[n0 + 32 + lr];
        #pragma unroll
        for (int r = 0; r < 4; r++){
            const int pl = lg * 4 + r;
            u_t[pl][n0 + lr]      = gelu_f(ac0[r] + b0);
            u_t[pl][n0 + 16 + lr] = gelu_f(ac1[r] + b1);
            u_t[pl][n0 + 32 + lr] = gelu_f(ac2[r] + b2);
        }
    }
    __syncthreads();

    // coalesced u plane stores (4 thr/plane, float4 of 4 consecutive positions)
    {
        float* __restrict__ u_ws = ws + OFF_U;
        #pragma unroll
        for (int pass = 0; pass < 3; pass++){
            const int plane = pass * 64 + (tid >> 2);
            const int posq = (tid & 3) * 4;
            float4 v = make_float4(u_t[posq + 0][plane], u_t[posq + 1][plane],
                                   u_t[posq + 2][plane], u_t[posq + 3][plane]);
            *(float4*)&u_ws[(size_t)(b * 192 + plane) * 4096 + prel + posq] = v;
        }
    }

    // ---- G2: [dT | dL | BC] = u @ Wcomb^T ; tiles: wv0:0-6 wv1:7-13 wv2:14-20 wv3:21-26 ----
    short8v uh[6], ul[6];
    #pragma unroll
    for (int ks = 0; ks < 6; ks++){
        const float* up = &u_t[lr][ks * 32 + lg * 8];
        split8(*(const float4*)up, *(const float4*)(up + 4), uh[ks], ul[ks]);
    }
    const int t0 = wv * 7 - (wv == 3 ? 0 : 0);           // 0,7,14,21
    const int cnt = (wv == 3) ? 6 : 7;
    for (int tp = 0; tp < cnt; tp += 2){
        const bool dual = (tp + 1 < cnt);
        const int n0a = (t0 + tp) * 16, n0b = dual ? (t0 + tp + 1) * 16 : n0a;
        floatx4 acA = {0.f,0.f,0.f,0.f}, acB = {0.f,0.f,0.f,0.f};
        #pragma unroll
        for (int ks = 0; ks < 6; ks++){
            const size_t ra = (size_t)(n0a + lr) * 192 + ks * 32 + lg * 8;
            const short8v bhA = *(const short8v*)(wsu + SW_WCH + ra);
            const short8v blA = *(const short8v*)(wsu + SW_WCL + ra);
            acA = __builtin_amdgcn_mfma_f32_16x16x32_bf16(uh[ks], bhA, acA, 0, 0, 0);
            acA = __builtin_amdgcn_mfma_f32_16x16x32_bf16(uh[ks], blA, acA, 0, 0, 0);
            acA = __builtin_amdgcn_mfma_f32_16x16x32_bf16(ul[ks], bhA, acA, 0, 0, 0);
            if (dual){
                const size_t rbb = (size_t)(n0b + lr) * 192 + ks * 32 + lg * 8;
                const short8v bhB = *(const short8v*)(wsu + SW_WCH + rbb);
                const short8v blB = *(const short8v*)(wsu + SW_WCL + rbb);
                acB = __builtin_amdgcn_mfma_f32_16x16x32_bf16(uh[ks], bhB, acB, 0, 0, 0);
                acB = __builtin_amdgcn_mfma_f32_16x16x32_bf16(uh[ks], blB, acB, 0, 0, 0);
                acB = __builtin_amdgcn_mfma_f32_16x16x32_bf16(ul[ks], bhB, acB, 0, 0, 0);
            }
        }
        #pragma unroll
        for (int half = 0; half < 2; half++){
            if (half == 1 && !dual) break;
            const floatx4 ac = half ? acB : acA;
            const int o = (half ? n0b : n0a) + lr;
            float bb = 0.f; int mode = 2;
            if (o < 192){ bb = dtTb[o]; mode = 0; }
            else if (o < 384){ bb = dtLb[o - 192]; mode = 1; }
            #pragma unroll
            for (int r = 0; r < 4; r++){
                float v = ac[r];
                if (mode < 2) v = softplus_f(v + bb);
                g2[lg * 4 + r][o] = v;
            }
        }
    }
    __syncthreads();

    // coalesced dT / dL / BC stores
    {
        float* __restrict__ dT_ws = ws + OFF_DT;
        float* __restrict__ dL_ws = ws + OFF_DL;
        const int plane = tid >> 2;               // 0..63
        const int posq = (tid & 3) * 4;
        #pragma unroll
        for (int pass = 0; pass < 3; pass++){
            const int o = pass * 64 + plane;
            float4 vT = make_float4(g2[posq + 0][o], g2[posq + 1][o],
                                    g2[posq + 2][o], g2[posq + 3][o]);
            float4 vL = make_float4(g2[posq + 0][192 + o], g2[posq + 1][192 + o],
                                    g2[posq + 2][192 + o], g2[posq + 3][192 + o]);
            *(float4*)&dT_ws[(size_t)(b * 192 + o) * 4096 + prel + posq] = vT;
            *(float4*)&dL_ws[(size_t)(b * 192 + o) * 4096 + prel + posq] = vL;
        }
        if (tid < 192){
            const int pl = tid >> 4;              // 0..11
            const int pos = tid & 15;
            float4 v = *(float4*)&g2[pos][384 + pl * 4];
            float4* dst = (float4*)(ws + OFF_BC3) + (size_t)(b * 12 + pl) * 4096 + prel + pos;
            *dst = v;
        }
    }
}

// ---------------- repack scalar planes (u,dT,dL) row-major -> packed diag ----------------
__global__ __launch_bounds__(256) void repack_k(float* __restrict__ ws){
    __shared__ float ldsf[4096];
    const int p = blockIdx.x;                   // 0..1151
    const float4* __restrict__ src4 = (const float4*)(ws + OFF_U + (size_t)p * 4096);
    float* __restrict__ dst = ws + OFF_DIAG + (size_t)p * 4096;
    const int tid = threadIdx.x;
    float4* lds4 = (float4*)ldsf;
    #pragma unroll
    for (int k = 0; k < 4; k++) lds4[tid + k * 256] = src4[tid + k * 256];
    __syncthreads();
    const int wv = tid >> 6, j2 = tid & 63;
    for (int s = wv; s < 127; s += 4){
        const int jmin = (s > 63) ? (s - 63) : 0;
        const int jmax = (s < 63) ? s : 63;
        const int len = jmax - jmin + 1;
        if (j2 < len){
            const int j = jmin + j2;
            dst[diag_off(s) + j2] = ldsf[(s - j) * 64 + j];
        }
    }
}

// ---------------- repack BC float4 planes row-major -> packed diag ----------------
__global__ __launch_bounds__(256) void repackbc_k(float* __restrict__ ws){
    __shared__ float4 l4[4096];                 // 64 KB
    const int p = blockIdx.x;                   // 0..23
    const float4* __restrict__ src = (const float4*)(ws + OFF_BC3) + (size_t)p * 4096;
    float4* __restrict__ dst = (float4*)(ws + OFF_BC4D) + (size_t)p * 4096;
    const int tid = threadIdx.x;
    #pragma unroll
    for (int k = 0; k < 16; k++) l4[tid + k * 256] = src[tid + k * 256];
    __syncthreads();
    const int wv = tid >> 6, j2 = tid & 63;
    for (int s = wv; s < 127; s += 4){
        const int jmin = (s > 63) ? (s - 63) : 0;
        const int jmax = (s < 63) ? s : 63;
        const int len = jmax - jmin + 1;
        if (j2 < len){
            const int j = jmin + j2;
            dst[diag_off(s) + j2] = l4[(s - j) * 64 + j];
        }
    }
}

// ---------------- diagonal wavefront scan (unchanged) ----------------
#define LOADSET(pfx, sv) do {                                                   \
    const int sv_ = (sv);                                                       \
    const int sc_ = sv_ < 126 ? sv_ : 126;                                      \
    const int jmin_ = (sc_ > 63) ? (sc_ - 63) : 0;                              \
    pfx##_q = diag_off(sc_) - jmin_ + j;                                        \
    pfx##_dT = pdT[pfx##_q]; pfx##_dL = pdL[pfx##_q]; pfx##_u = pu[pfx##_q];    \
    pfx##_bt = pBT[pfx##_q]; pfx##_bl = pBL[pfx##_q]; pfx##_cc = pC[pfx##_q];   \
} while (0)

#define STEP(pfx, sv) do {                                                      \
    const float dT_ = pfx##_dT, dL_ = pfx##_dL, u_ = pfx##_u;                   \
    const float bt_[4] = {pfx##_bt.x, pfx##_bt.y, pfx##_bt.z, pfx##_bt.w};      \
    const float bl_[4] = {pfx##_bl.x, pfx##_bl.y, pfx##_bl.z, pfx##_bl.w};      \
    const float cc_[4] = {pfx##_cc.x, pfx##_cc.y, pfx##_cc.z, pfx##_cc.w};      \
    const int q_ = pfx##_q;                                                     \
    LOADSET(pfx, (sv) + 3);                                                     \
    float da_[4], dl_[4];                                                       \
    if (sflag){                                                                 \
        const float E_ = __expf(-dT_), F_ = __expf(-dL_);                       \
        da_[0] = __expf(nA1 * dT_); dl_[0] = __expf(nA1 * dL_);                 \
        da_[1] = da_[0] * E_; da_[2] = da_[1] * E_; da_[3] = da_[2] * E_;       \
        dl_[1] = dl_[0] * F_; dl_[2] = dl_[1] * F_; dl_[3] = dl_[2] * F_;       \
    } else {                                                                    \
        da_[0] = __expf(dT_ * ATr[0]); da_[1] = __expf(dT_ * ATr[1]);           \
        da_[2] = __expf(dT_ * ATr[2]); da_[3] = __expf(dT_ * ATr[3]);           \
        dl_[0] = __expf(dL_ * ALr[0]); dl_[1] = __expf(dL_ * ALr[1]);           \
        dl_[2] = __expf(dL_ * ALr[2]); dl_[3] = __expf(dL_ * ALr[3]);           \
    }                                                                           \
    const int ic_ = (sv) - j;                                                   \
    const bool act_ = ((unsigned)ic_) < 64u;                                    \
    const float udT_ = u_ * dT_, udL_ = u_ * dL_;                               \
    float y_ = 0.f;                                                             \
    _Pragma("unroll")                                                           \
    for (int k = 0; k < 4; k++){                                                \
        float hl_ = __shfl_up(h[k], 1u, 64);                                    \
        hl_ = (j == 0) ? 0.f : hl_;                                             \
        float hn_ = fmaf(da_[k], h[k], fmaf(dl_[k], hl_, fmaf(udT_, bt_[k], udL_ * bl_[k]))); \
        h[k] = act_ ? hn_ : h[k];                                               \
        y_ = fmaf(hn_, cc_[k], y_);                                             \
    }                                                                           \
    if (act_) ylds[wv][q_] = y_;                                                \
} while (0)

__global__ __launch_bounds__(128) void scan_k(const float* __restrict__ ATl,
                                              const float* __restrict__ ALl,
                                              float* __restrict__ ws){
    __shared__ float ylds[2][4096];             // 32 KB
    const int bx = blockIdx.x;
    const int bd = bx >> 1, half = bx & 1;
    const int b = bd / 192, d = bd - b * 192;
    const int tid = threadIdx.x;
    const int wv = tid >> 6, j = tid & 63;
    const int n0 = half * 8 + wv * 4;
    const int ng = half * 2 + wv;

    const float* __restrict__ pu  = ws + OFF_DIAG + (size_t)bd * 4096;
    const float* __restrict__ pdT = ws + OFF_DIAG + (size_t)(384 + bd) * 4096;
    const float* __restrict__ pdL = ws + OFF_DIAG + (size_t)(768 + bd) * 4096;
    const float4* __restrict__ bc4 = (const float4*)(ws + OFF_BC4D) + (size_t)(b * 12) * 4096;
    const float4* __restrict__ pBT = bc4 + (size_t)(0 + ng) * 4096;
    const float4* __restrict__ pBL = bc4 + (size_t)(4 + ng) * 4096;
    const float4* __restrict__ pC  = bc4 + (size_t)(8 + ng) * 4096;
    float* __restrict__ pY = ws + (half ? OFF_DL : OFF_U) + (size_t)bd * 4096;

    const bool sflag = (ws[OFF_FLAG] > 0.5f);
    const float nA1 = -(float)(n0 + 1);
    float ATr[4], ALr[4];
    if (!sflag){
        #pragma unroll
        for (int k = 0; k < 4; k++){
            ATr[k] = -expf(ATl[d * NS + n0 + k]);
            ALr[k] = -expf(ALl[d * NS + n0 + k]);
        }
    } else {
        #pragma unroll
        for (int k = 0; k < 4; k++){ ATr[k] = 0.f; ALr[k] = 0.f; }
    }
    float h[4] = {0.f, 0.f, 0.f, 0.f};

    int a_q, b_q, c_q;
    float a_dT, a_dL, a_u; float4 a_bt, a_bl, a_cc;
    float b_dT, b_dL, b_u; float4 b_bt, b_bl, b_cc;
    float c_dT, c_dL, c_u; float4 c_bt, c_bl, c_cc;
    LOADSET(a, 0);
    LOADSET(b, 1);
    LOADSET(c, 2);

    for (int s = 0; s < 129; s += 3){
        STEP(a, s);
        STEP(b, s + 1);
        STEP(c, s + 2);
    }

    __syncthreads();
    for (int idx = tid; idx < 4096; idx += 128)
        pY[idx] = ylds[0][idx] + ylds[1][idx];
}

// ---------------- y-sum + gelu (diag -> row-major YG planes in OFF_DT) ----------------
__global__ __launch_bounds__(256) void ysum_k(const float* __restrict__ Dskp,
                                              float* __restrict__ ws){
    __shared__ float yl[4096];
    const int bd = blockIdx.x;
    const int d = bd % 192;
    const int tid = threadIdx.x;
    const float* __restrict__ p0 = ws + OFF_U  + (size_t)bd * 4096;
    const float* __restrict__ p1 = ws + OFF_DL + (size_t)bd * 4096;
    const float* __restrict__ pu = ws + OFF_DIAG + (size_t)bd * 4096;
    float* __restrict__ yg = ws + OFF_DT + (size_t)bd * 4096;
    const float Dsk = Dskp[d];
    #pragma unroll
    for (int k = 0; k < 16; k++){
        const int idx = tid + k * 256;
        yl[idx] = gelu_f(p0[idx] + p1[idx] + pu[idx] * Dsk);
    }
    __syncthreads();
    #pragma unroll
    for (int k = 0; k < 16; k++){
        const int idx = tid + k * 256;
        const int i = idx >> 6, jj = idx & 63;
        const int s = i + jj;
        const int jmin = (s > 63) ? (s - 63) : 0;
        yg[idx] = yl[diag_off(s) + jj - jmin];
    }
}

// ---------------- out projection via bf16x3 MFMA ----------------
// 512 blocks x 256 thr (4 waves), 16 positions per block; wave wv -> n-tiles wv*3..wv*3+2.
__global__ __launch_bounds__(256) void out_k(const float* __restrict__ Wob,
                                             float* __restrict__ ws,
                                             float* __restrict__ out){
    __shared__ float yg_t[16][196];
    const unsigned short* __restrict__ wsu = (const unsigned short*)ws;
    const int P0 = blockIdx.x * 16;
    const int b = P0 >> 12;
    const int prel = P0 & 4095;
    const int tid = threadIdx.x;

    // coalesced staged read: yg planes [d][pos] -> LDS [pos][d]
    {
        const float* __restrict__ ygp = ws + OFF_DT;
        #pragma unroll
        for (int pass = 0; pass < 3; pass++){
            const int plane = pass * 64 + (tid >> 2);
            const int posq = (tid & 3) * 4;
            float4 v = *(const float4*)&ygp[(size_t)(b * 192 + plane) * 4096 + prel + posq];
            yg_t[posq + 0][plane] = v.x;
            yg_t[posq + 1][plane] = v.y;
            yg_t[posq + 2][plane] = v.z;
            yg_t[posq + 3][plane] = v.w;
        }
    }
    __syncthreads();

    const int wv = tid >> 6, lane = tid & 63;
    const int lr = lane & 15, lg = lane >> 4;

    short8v yh[6], yl2[6];
    #pragma unroll
    for (int ks = 0; ks < 6; ks++){
        const float* yp = &yg_t[lr][ks * 32 + lg * 8];
        split8(*(const float4*)yp, *(const float4*)(yp + 4), yh[ks], yl2[ks]);
    }
    {
        floatx4 ac0 = {0.f,0.f,0.f,0.f}, ac1 = {0.f,0.f,0.f,0.f}, ac2 = {0.f,0.f,0.f,0.f};
        const int n0 = wv * 48;
        #pragma unroll
        for (int ks = 0; ks < 6; ks++){
            const size_t rb = (size_t)(n0 + lr) * 192 + ks * 32 + lg * 8;
            const short8v bh0 = *(const short8v*)(wsu + SW_WOH + rb);
            const short8v bl0 = *(const short8v*)(wsu + SW_WOL + rb);
            const short8v bh1 = *(const short8v*)(wsu + SW_WOH + rb + 16*192);
            const short8v bl1 = *(const short8v*)(wsu + SW_WOL + rb + 16*192);
            const short8v bh2 = *(const short8v*)(wsu + SW_WOH + rb + 32*192);
            const short8v bl2 = *(const short8v*)(wsu + SW_WOL + rb + 32*192);
            ac0 = __builtin_amdgcn_mfma_f32_16x16x32_bf16(yh[ks], bh0, ac0, 0, 0, 0);
            ac1 = __builtin_amdgcn_mfma_f32_16x16x32_bf16(yh[ks], bh1, ac1, 0, 0, 0);
            ac2 = __builtin_amdgcn_mfma_f32_16x16x32_bf16(yh[ks], bh2, ac2, 0, 0, 0);
            ac0 = __builtin_amdgcn_mfma_f32_16x16x32_bf16(yh[ks], bl0, ac0, 0, 0, 0);
            ac1 = __builtin_amdgcn_mfma_f32_16x16x32_bf16(yh[ks], bl1, ac1, 0, 0, 0);
            ac2 = __builtin_amdgcn_mfma_f32_16x16x32_bf16(yh[ks], bl2, ac2, 0, 0, 0);
            ac0 = __builtin_amdgcn_mfma_f32_16x16x32_bf16(yl2[ks], bh0, ac0, 0, 0, 0);
            ac1 = __builtin_amdgcn_mfma_f32_16x16x32_bf16(yl2[ks], bh1, ac1, 0, 0, 0);
            ac2 = __builtin_amdgcn_mfma_f32_16x16x32_bf16(yl2[ks], bh2, ac2, 0, 0, 0);
        }
        const float b0 = Wob[n0 + lr], b1 = Wob[n0 + 16 + lr], b2 = Wob[n0 + 32 + lr];
        #pragma unroll
        for (int r = 0; r < 4; r++){
            const int pos = P0 + lg * 4 + r;
            out[(size_t)pos * 192 + n0 + lr]      = ac0[r] + b0;
            out[(size_t)pos * 192 + n0 + 16 + lr] = ac1[r] + b1;
            out[(size_t)pos * 192 + n0 + 32 + lr] = ac2[r] + b2;
        }
    }
}

extern "C" void kernel_launch(void* const* d_in, const int* in_sizes, int n_in,
                              void* d_out, int out_size, void* d_ws, size_t ws_size,
                              hipStream_t stream) {
    const float* x    = (const float*)d_in[0];
    const float* Win  = (const float*)d_in[1];
    const float* Winb = (const float*)d_in[2];
    const float* xpw  = (const float*)d_in[3];
    const float* dtTw = (const float*)d_in[4];
    const float* dtTb = (const float*)d_in[5];
    const float* dtLw = (const float*)d_in[6];
    const float* dtLb = (const float*)d_in[7];
    const float* ATl  = (const float*)d_in[8];
    const float* ALl  = (const float*)d_in[9];
    const float* Dsk  = (const float*)d_in[10];
    const float* Wo   = (const float*)d_in[11];
    const float* Wob  = (const float*)d_in[12];
    float* out = (float*)d_out;
    float* ws  = (float*)d_ws;

    hipLaunchKernelGGL(prep_k,     dim3(613),  dim3(256), 0, stream, Win, xpw, dtTw, dtLw, Wo, ATl, ALl, ws);
    hipLaunchKernelGGL(proj_k,     dim3(512),  dim3(256), 0, stream, x, Winb, dtTb, dtLb, ws);
    hipLaunchKernelGGL(repack_k,   dim3(1152), dim3(256), 0, stream, ws);
    hipLaunchKernelGGL(repackbc_k, dim3(24),   dim3(256), 0, stream, ws);
    hipLaunchKernelGGL(scan_k,     dim3(768),  dim3(128), 0, stream, ATl, ALl, ws);
    hipLaunchKernelGGL(ysum_k,     dim3(384),  dim3(256), 0, stream, Dsk, ws);
    hipLaunchKernelGGL(out_k,      dim3(512),  dim3(256), 0, stream, Wob, ws, out);
}